// Round 4
// baseline (348.002 us; speedup 1.0000x reference)
//
#include <hip/hip_runtime.h>
#include <hip/hip_bf16.h>
#include <stdint.h>

// GCN: out = Dinv (A+I) Dinv (X W) + b, two layers, relu between.
// N=100000, E=1600000, K=128, C1=128, C2=64. fp32 in/out (edge_index int32).
// R13: fusion REVERTED (R12->R13: occupancy 73->35%, gather fetch 3.5->2.0 TB/s;
//   the random gather needs ~23 waves/CU of MLP -- keep it LDS-free, 24 VGPR).
//   This round:
//   - back to split R11 structure (best measured), CHUNK=4096 kept
//   - gather128 split into two half-N dispatches (diagnostic: exposes any middle
//     kernel >=33us in next round's top-5 counter table; cost ~1us)
//   - deg counting moved into multisplit (global atomicAdd degN); bucket_build
//     drops its count pass over packed (was 1 block/CU, 1 wave/SIMD -- serial)
//   Kept: quarter/octave-wave dwordx4 gathers, pk_add f32x2 acc, 32-bit saddr
//   offsets, fixed-capacity buckets, MFMA GEMMs, bucket-local csr fill, BSH=9.

static constexpr int KD = 128;
static constexpr int BSH = 9;                  // nodes per bucket = 512
static constexpr int MAXB = 256;               // max buckets supported
static constexpr int CHUNK = 4096;             // edges per multisplit block
static constexpr int CAP = 12288;              // bucket cap (mean 8192 + ~45 sigma)

typedef short bf16x8 __attribute__((ext_vector_type(8)));
typedef float f32x4  __attribute__((ext_vector_type(4)));
typedef float f32x2  __attribute__((ext_vector_type(2)));

__device__ __forceinline__ unsigned short f2bf(float f) {
    __hip_bfloat16 b = __float2bfloat16(f);    // RNE
    return *reinterpret_cast<unsigned short*>(&b);
}
__device__ __forceinline__ float bflo(unsigned v) { return __uint_as_float(v << 16); }
__device__ __forceinline__ float bfhi(unsigned v) { return __uint_as_float(v & 0xffff0000u); }
__device__ __forceinline__ unsigned pk2(float lo, float hi) {
    return (unsigned)f2bf(lo) | ((unsigned)f2bf(hi) << 16);
}
// packed accumulate: 2 unpack + 1 v_pk_add_f32 per u32
__device__ __forceinline__ void accp(f32x2* a, uint4 v) {
    f32x2 t;
    t.x = bflo(v.x); t.y = bfhi(v.x); a[0] += t;
    t.x = bflo(v.y); t.y = bfhi(v.y); a[1] += t;
    t.x = bflo(v.z); t.y = bfhi(v.z); a[2] += t;
    t.x = bflo(v.w); t.y = bfhi(v.w); a[3] += t;
}

// ------- init: W transpose to bf16 + bucket cursor init + degN zero -------
__global__ __launch_bounds__(256) void init_misc(const float* __restrict__ W1,
        const float* __restrict__ W2, unsigned short* __restrict__ Wt1,
        unsigned short* __restrict__ Wt2, int* __restrict__ bcur,
        int* __restrict__ degN, int nbuck, int n) {
    int t = blockIdx.x * 256 + threadIdx.x;
    if (t < 128 * 128) {
        int k = t >> 7, nn = t & 127;
        Wt1[nn * 128 + k] = f2bf(W1[t]);
    } else if (t < 128 * 128 + 128 * 64) {
        int i = t - 128 * 128;
        int k = i >> 6, nn = i & 63;
        Wt2[nn * 128 + k] = f2bf(W2[i]);
    } else if (t < 128 * 128 + 128 * 64 + MAXB) {
        int b = t - (128 * 128 + 128 * 64);
        bcur[b] = b * CAP;
    } else {
        int i = t - (128 * 128 + 128 * 64 + MAXB);
        if (i < n) degN[i] = 0;
    }
}

// ---------------- multisplit into fixed-capacity bucket regions ----------------
// packed edge = (dstLocal << 22) | src   (src < 2^22, dstLocal < 512)
// Also accumulates degN (global atomics) so bucket_build needs no count pass.
__global__ __launch_bounds__(256) void multisplit(const int* __restrict__ src,
        const int* __restrict__ dst, int* __restrict__ bcur, int* __restrict__ degN,
        int* __restrict__ packed, int e, int nbuck) {
    __shared__ int cnt[MAXB], lbase[MAXB], wbase[MAXB], vcnt[MAXB], scanbuf[256];
    __shared__ int buf[CHUNK];
    const int t = threadIdx.x;
    const int e0 = blockIdx.x * CHUNK;
    const int m = min(CHUNK, e - e0);

    for (int i = t; i < nbuck; i += 256) cnt[i] = 0;
    __syncthreads();
    for (int i = t; i < m; i += 256) {
        int d = dst[e0 + i];
        atomicAdd(&cnt[d >> BSH], 1);
        atomicAdd(&degN[d], 1);
    }
    __syncthreads();
    int v = (t < nbuck) ? cnt[t] : 0;
    scanbuf[t] = v;
    __syncthreads();
    for (int off = 1; off < 256; off <<= 1) {
        int u = (t >= off) ? scanbuf[t - off] : 0;
        __syncthreads();
        scanbuf[t] += u;
        __syncthreads();
    }
    int excl = scanbuf[t] - v;
    if (t < nbuck) {
        lbase[t] = excl;
        vcnt[t] = v;
        wbase[t] = v ? atomicAdd(&bcur[t], v) : 0;
        cnt[t] = excl;              // becomes local cursor
    }
    __syncthreads();
    for (int i = t; i < m; i += 256) {
        int d = dst[e0 + i], s = src[e0 + i];
        int b = d >> BSH;
        int p = atomicAdd(&cnt[b], 1);
        buf[p] = ((d & ((1 << BSH) - 1)) << 22) | s;
    }
    __syncthreads();
    int wv = t >> 6, ln = t & 63;
    for (int b = wv; b < nbuck; b += 4) {
        int c = vcnt[b], st = lbase[b], g = wbase[b];
        int end = min(c, (b + 1) * CAP - g);    // overflow guard (never expected)
        for (int i = ln; i < end; i += 64) packed[g + i] = buf[st + i];
    }
}

// -------- per-bucket roff/dinv/csr (deg comes from global degN now) --------
__global__ __launch_bounds__(256) void bucket_build(const int* __restrict__ packed,
        const int* __restrict__ bcur, int* __restrict__ roff,
        const int* __restrict__ degN, float* __restrict__ dinv,
        int* __restrict__ csr, int n) {
    __shared__ int cur[1 << BSH];
    __shared__ int wsum[4];
    const int t = threadIdx.x;
    const int b = blockIdx.x;
    const int nodeBase = b << BSH;
    const int nn = min(1 << BSH, n - nodeBase);
    const int e0 = b * CAP, e1 = bcur[b];

    const int i0 = t * 2;
    int d0 = (i0     < nn) ? degN[nodeBase + i0]     : 0;
    int d1 = (i0 + 1 < nn) ? degN[nodeBase + i0 + 1] : 0;
    int tsum = d0 + d1;
    int lane = t & 63, wv = t >> 6;
    int v = tsum;
    for (int off = 1; off < 64; off <<= 1) {
        int u = __shfl_up(v, off, 64);
        if (lane >= off) v += u;
    }
    if (lane == 63) wsum[wv] = v;
    __syncthreads();
    int woff = 0;
    for (int i = 0; i < wv; ++i) woff += wsum[i];
    int excl = v - tsum + woff;
    int p0 = excl, p1 = excl + d0;
    cur[i0] = p0; cur[i0 + 1] = p1;
    if (i0 < nn) {
        roff[nodeBase + i0] = e0 + p0;
        dinv[nodeBase + i0] = rsqrtf((float)(d0 + 1));
    }
    if (i0 + 1 < nn) {
        roff[nodeBase + i0 + 1] = e0 + p1;
        dinv[nodeBase + i0 + 1] = rsqrtf((float)(d1 + 1));
    }
    __syncthreads();

    for (int i = e0 + t; i < e1; i += 256) {
        unsigned pk = (unsigned)packed[i];
        int dl = pk >> 22;
        int s = pk & 0x3FFFFF;
        int slot = atomicAdd(&cur[dl], 1);
        csr[e0 + slot] = s;
    }
}

// ---------------- MFMA GEMM: out_bf[i][c] = bf16(dinv[i] * sum_k x[i][k]*W[k][c]) ----
// 64 rows x C cols per block, 4 waves. XBF: input already bf16.
template<int C, bool XBF>
__global__ __launch_bounds__(256) void gemm_mfma(const void* __restrict__ xv,
        const unsigned short* __restrict__ Wt, const float* __restrict__ dinv,
        unsigned short* __restrict__ out, int n)
{
    constexpr int KP = KD + 8;                 // 136 shorts = 272B row stride
    constexpr int WP = 64 + 8;                 // 72 shorts = 144B row stride
    __shared__ __align__(16) unsigned short xt[64 * KP];
    __shared__ __align__(16) unsigned short lw[C * WP];
    const int t = threadIdx.x;
    const int w = t >> 6, lane = t & 63;
    const int quad = lane >> 4, l16 = lane & 15;
    const int row0 = blockIdx.x * 64;

    // stage x tile (4 cols per iter)
    for (int i = t; i < 64 * 32; i += 256) {
        int r = i >> 5, c4 = (i & 31) * 4;
        int row = row0 + r;
        ushort4 pk = make_ushort4(0, 0, 0, 0);
        if (row < n) {
            if constexpr (XBF) {
                pk = *reinterpret_cast<const ushort4*>(
                    &((const unsigned short*)xv)[(size_t)row * KD + c4]);
            } else {
                float4 v = *reinterpret_cast<const float4*>(
                    &((const float*)xv)[(size_t)row * KD + c4]);
                pk.x = f2bf(v.x); pk.y = f2bf(v.y); pk.z = f2bf(v.z); pk.w = f2bf(v.w);
            }
        }
        *reinterpret_cast<ushort4*>(&xt[r * KP + c4]) = pk;
    }

    f32x4 acc[C / 16];
#pragma unroll
    for (int i = 0; i < C / 16; ++i) acc[i] = (f32x4)(0.f);

    for (int h = 0; h < 2; ++h) {
        __syncthreads();   // h=0: covers xt writes; h=1: waits for lw readers
        for (int i = t; i < C * 16; i += 256) {       // 8B chunks, 16 per Wt half-row
            int nr = i >> 4, j = (i & 15) * 4;
            *reinterpret_cast<ushort4*>(&lw[nr * WP + j]) =
                *reinterpret_cast<const ushort4*>(&Wt[nr * KD + h * 64 + j]);
        }
        __syncthreads();
#pragma unroll
        for (int kt = 0; kt < 2; ++kt) {
            bf16x8 af = *reinterpret_cast<const bf16x8*>(
                &xt[(w * 16 + l16) * KP + h * 64 + kt * 32 + quad * 8]);
#pragma unroll
            for (int ct = 0; ct < C / 16; ++ct) {
                bf16x8 bfr = *reinterpret_cast<const bf16x8*>(
                    &lw[(ct * 16 + l16) * WP + kt * 32 + quad * 8]);
                acc[ct] = __builtin_amdgcn_mfma_f32_16x16x32_bf16(af, bfr, acc[ct], 0, 0, 0);
            }
        }
    }

    // epilogue: D layout col = ct*16 + l16, row = quad*4 + j
#pragma unroll
    for (int j = 0; j < 4; ++j) {
        int row = row0 + w * 16 + quad * 4 + j;
        if (row < n) {
            float s = dinv[row];
#pragma unroll
            for (int ct = 0; ct < C / 16; ++ct)
                out[(size_t)row * C + ct * 16 + l16] = f2bf(acc[ct][j] * s);
        }
    }
}

// ---------------- gather128: quarter-wave dwordx4, 4 edges per load instr -------
// h1 row = 128 bf16 = 256B = 16 lanes x uint4. qw=lane>>4 handles edges j+qw,
// j+4+qw of each 8-block; quarters combined via shfl_xor(16|32).
// Node range [n0, n1): launched as two half dispatches (diagnostic + same perf).
__global__ __launch_bounds__(256) void gather128(const uint4* __restrict__ H,
        const int* __restrict__ roff, const int* __restrict__ degN,
        const int* __restrict__ csr, const float* __restrict__ dinv,
        const float* __restrict__ b, uint4* __restrict__ out, int n0, int n1)
{
    int wid = n0 + ((blockIdx.x * 256 + threadIdx.x) >> 6);
    int lane = threadIdx.x & 63;
    if (wid >= n1) return;
    const int qw = lane >> 4, cp = lane & 15;
    const char* Hb = (const char*)H;
    const unsigned cpo = (unsigned)cp * 16u;
    f32x2 a[4], c[4];
#pragma unroll
    for (int i = 0; i < 4; ++i) { a[i] = (f32x2)(0.f); c[i] = (f32x2)(0.f); }
    int e0 = roff[wid], e1 = e0 + degN[wid];
    for (int base = e0; base < e1; base += 64) {
        int m = e1 - base; if (m > 64) m = 64;
        int idx = (lane < m) ? csr[base + lane] : 0;
        int j = 0;
        for (; j + 8 <= m; j += 8) {
            unsigned u0 = (unsigned)__shfl(idx, j + qw);
            unsigned u1 = (unsigned)__shfl(idx, j + 4 + qw);
            uint4 v0 = *(const uint4*)(Hb + ((u0 << 8) + cpo));
            uint4 v1 = *(const uint4*)(Hb + ((u1 << 8) + cpo));
            accp(a, v0);
            accp(c, v1);
        }
        for (; j + 4 <= m; j += 4) {
            unsigned u = (unsigned)__shfl(idx, j + qw);
            uint4 v = *(const uint4*)(Hb + ((u << 8) + cpo));
            accp(a, v);
        }
        int r = m - j;
        if (r) {
            unsigned u = (unsigned)__shfl(idx, min(j + qw, m - 1));  // uniform-active shfl
            if (qw < r) {
                uint4 v = *(const uint4*)(Hb + ((u << 8) + cpo));
                accp(a, v);
            }
        }
    }
#pragma unroll
    for (int i = 0; i < 4; ++i) a[i] += c[i];
#pragma unroll
    for (int i = 0; i < 4; ++i) {
        a[i].x += __shfl_xor(a[i].x, 16, 64);
        a[i].x += __shfl_xor(a[i].x, 32, 64);
        a[i].y += __shfl_xor(a[i].y, 16, 64);
        a[i].y += __shfl_xor(a[i].y, 32, 64);
    }
    if (qw == 0) {
        uint4 sv = *(const uint4*)(Hb + (((unsigned)wid << 8) + cpo));  // self loop
        accp(a, sv);
        float s = dinv[wid];
        float4 b0 = ((const float4*)b)[cp * 2];
        float4 b1 = ((const float4*)b)[cp * 2 + 1];
        float r0 = fmaxf(s * a[0].x + b0.x, 0.f), r1 = fmaxf(s * a[0].y + b0.y, 0.f);
        float r2 = fmaxf(s * a[1].x + b0.z, 0.f), r3 = fmaxf(s * a[1].y + b0.w, 0.f);
        float r4 = fmaxf(s * a[2].x + b1.x, 0.f), r5 = fmaxf(s * a[2].y + b1.y, 0.f);
        float r6 = fmaxf(s * a[3].x + b1.z, 0.f), r7 = fmaxf(s * a[3].y + b1.w, 0.f);
        uint4 o;
        o.x = pk2(r0, r1); o.y = pk2(r2, r3); o.z = pk2(r4, r5); o.w = pk2(r6, r7);
        out[(size_t)wid * 16 + cp] = o;
    }
}

// ---------------- gather64: octave-wave dwordx4, 8 edges per load instr ---------
// h2 row = 64 bf16 = 128B = 8 lanes x uint4. oc=lane>>3 handles edge j+oc (and
// j+8+oc in the 16-block); octaves combined via shfl_xor(8|16|32).
__global__ __launch_bounds__(256) void gather64(const uint4* __restrict__ H,
        const int* __restrict__ roff, const int* __restrict__ degN,
        const int* __restrict__ csr, const float* __restrict__ dinv,
        const float* __restrict__ b, float4* __restrict__ out, int n)
{
    int wid = (blockIdx.x * 256 + threadIdx.x) >> 6;
    int lane = threadIdx.x & 63;
    if (wid >= n) return;
    const int oc = lane >> 3, cp = lane & 7;
    const char* Hb = (const char*)H;
    const unsigned cpo = (unsigned)cp * 16u;
    f32x2 a[4], c[4];
#pragma unroll
    for (int i = 0; i < 4; ++i) { a[i] = (f32x2)(0.f); c[i] = (f32x2)(0.f); }
    int e0 = roff[wid], e1 = e0 + degN[wid];
    for (int base = e0; base < e1; base += 64) {
        int m = e1 - base; if (m > 64) m = 64;
        int idx = (lane < m) ? csr[base + lane] : 0;
        int j = 0;
        for (; j + 16 <= m; j += 16) {
            unsigned u0 = (unsigned)__shfl(idx, j + oc);
            unsigned u1 = (unsigned)__shfl(idx, j + 8 + oc);
            uint4 v0 = *(const uint4*)(Hb + ((u0 << 7) + cpo));
            uint4 v1 = *(const uint4*)(Hb + ((u1 << 7) + cpo));
            accp(a, v0);
            accp(c, v1);
        }
        for (; j + 8 <= m; j += 8) {
            unsigned u = (unsigned)__shfl(idx, j + oc);
            uint4 v = *(const uint4*)(Hb + ((u << 7) + cpo));
            accp(a, v);
        }
        int r = m - j;
        if (r) {
            unsigned u = (unsigned)__shfl(idx, min(j + oc, m - 1));  // uniform-active shfl
            if (oc < r) {
                uint4 v = *(const uint4*)(Hb + ((u << 7) + cpo));
                accp(a, v);
            }
        }
    }
#pragma unroll
    for (int i = 0; i < 4; ++i) a[i] += c[i];
#pragma unroll
    for (int i = 0; i < 4; ++i) {
        a[i].x += __shfl_xor(a[i].x, 8, 64);
        a[i].x += __shfl_xor(a[i].x, 16, 64);
        a[i].x += __shfl_xor(a[i].x, 32, 64);
        a[i].y += __shfl_xor(a[i].y, 8, 64);
        a[i].y += __shfl_xor(a[i].y, 16, 64);
        a[i].y += __shfl_xor(a[i].y, 32, 64);
    }
    if (oc == 0) {
        uint4 sv = *(const uint4*)(Hb + (((unsigned)wid << 7) + cpo));  // self loop
        accp(a, sv);
        float s = dinv[wid];
        float4 b0 = ((const float4*)b)[cp * 2];
        float4 b1 = ((const float4*)b)[cp * 2 + 1];
        float4 o0 = make_float4(s * a[0].x + b0.x, s * a[0].y + b0.y,
                                s * a[1].x + b0.z, s * a[1].y + b0.w);
        float4 o1 = make_float4(s * a[2].x + b1.x, s * a[2].y + b1.y,
                                s * a[3].x + b1.z, s * a[3].y + b1.w);
        out[(size_t)wid * 16 + cp * 2] = o0;
        out[(size_t)wid * 16 + cp * 2 + 1] = o1;
    }
}

extern "C" void kernel_launch(void* const* d_in, const int* in_sizes, int n_in,
                              void* d_out, int out_size, void* d_ws, size_t ws_size,
                              hipStream_t stream)
{
    const int* ei = (const int*)d_in[0];
    const int E = in_sizes[0] / 2;
    const float* emb = (const float*)d_in[1];
    const int N = in_sizes[1] / KD;
    const float* W1 = (const float*)d_in[2];
    const float* b1 = (const float*)d_in[3];
    const float* W2 = (const float*)d_in[4];
    const float* b2 = (const float*)d_in[5];
    const int* src = ei;        // edge_index[0]
    const int* dst = ei + E;    // edge_index[1]
    const int nbuck = (N + (1 << BSH) - 1) >> BSH;   // 196 for N=100000

    // ---- workspace layout ----
    char* p = (char*)d_ws;
    auto alloc = [&](size_t bytes) { char* q = p; p += (bytes + 255) & ~(size_t)255; return q; };
    unsigned short* h1 = (unsigned short*)alloc((size_t)N * 128 * sizeof(unsigned short)); // bf16
    unsigned short* x2 = (unsigned short*)alloc((size_t)N * 128 * sizeof(unsigned short)); // bf16
    int*   csr    = (int*)  alloc((size_t)nbuck * CAP * sizeof(int));
    int*   packed = (int*)  alloc((size_t)nbuck * CAP * sizeof(int));
    int*   roff   = (int*)  alloc((size_t)N * sizeof(int));
    int*   degN   = (int*)  alloc((size_t)N * sizeof(int));
    float* dinv   = (float*)alloc((size_t)N * sizeof(float));
    int*   bcur   = (int*)  alloc(MAXB * sizeof(int));
    unsigned short* Wt1 = (unsigned short*)alloc(128 * 128 * sizeof(unsigned short));
    unsigned short* Wt2 = (unsigned short*)alloc(64 * 128 * sizeof(unsigned short));
    unsigned short* h2 = h1;                        // bf16 [N,64], h1 dead after gather128

    // ---- CSR build ----
    const int initThreads = 128 * 128 + 128 * 64 + MAXB + N;
    init_misc<<<(initThreads + 255) / 256, 256, 0, stream>>>(W1, W2, Wt1, Wt2, bcur,
                                                             degN, nbuck, N);
    multisplit<<<(E + CHUNK - 1) / CHUNK, 256, 0, stream>>>(src, dst, bcur, degN,
                                                            packed, E, nbuck);
    bucket_build<<<nbuck, 256, 0, stream>>>(packed, bcur, roff, degN, dinv, csr, N);

    // ---- layer 1 ----
    gemm_mfma<128, false><<<(N + 63) / 64, 256, 0, stream>>>(emb, Wt1, dinv, h1, N);
    const int half = ((N / 2) + 63) & ~63;          // 50048
    gather128<<<half / 4, 256, 0, stream>>>((const uint4*)h1, roff, degN, csr,
                                            dinv, b1, (uint4*)x2, 0, half);
    gather128<<<(N - half + 3) / 4, 256, 0, stream>>>((const uint4*)h1, roff, degN, csr,
                                                      dinv, b1, (uint4*)x2, half, N);

    // ---- layer 2 ----
    gemm_mfma<64, true><<<(N + 63) / 64, 256, 0, stream>>>(x2, Wt2, dinv, h2, N);
    gather64<<<(N + 3) / 4, 256, 0, stream>>>((const uint4*)h2, roff, degN, csr,
                                              dinv, b2, (float4*)d_out, N);
}

// Round 5
// 302.734 us; speedup vs baseline: 1.1495x; 1.1495x over previous
//
#include <hip/hip_runtime.h>
#include <hip/hip_bf16.h>
#include <stdint.h>

// GCN: out = Dinv (A+I) Dinv (X W) + b, two layers, relu between.
// N=100000, E=1600000, K=128, C1=128, C2=64. fp32 in/out (edge_index int32).
// R14: multisplit exposed at 91us (occupancy 14.6%, VALU 3.7%, HBM 9% = pure
//   latency; degN device-scope atomics = memory-side RMW, +51MB WRITE). Replace
//   with atomic-free 3-phase partition, all phases highly parallel:
//     chunk_hist (782 blk, 1KB LDS) -> ghist[chunk][bucket]
//     chunk_scan (196 blk)          -> exact write base per (chunk,bucket), bcur
//     chunk_scatter (782 blk)       -> LDS cursor + direct global write
//   degN counting reverted into bucket_build (R2 form). gather128 half-split
//   diagnostic kept. Gathers/GEMMs untouched (gather128 at 3.5TB/s mem floor).

static constexpr int KD = 128;
static constexpr int BSH = 9;                  // nodes per bucket = 512
static constexpr int MAXB = 256;               // max buckets supported
static constexpr int CHUNK = 2048;             // edges per partition chunk
static constexpr int CAP = 12288;              // bucket cap (mean 8163 + ~45 sigma)

typedef short bf16x8 __attribute__((ext_vector_type(8)));
typedef float f32x4  __attribute__((ext_vector_type(4)));
typedef float f32x2  __attribute__((ext_vector_type(2)));

__device__ __forceinline__ unsigned short f2bf(float f) {
    __hip_bfloat16 b = __float2bfloat16(f);    // RNE
    return *reinterpret_cast<unsigned short*>(&b);
}
__device__ __forceinline__ float bflo(unsigned v) { return __uint_as_float(v << 16); }
__device__ __forceinline__ float bfhi(unsigned v) { return __uint_as_float(v & 0xffff0000u); }
__device__ __forceinline__ unsigned pk2(float lo, float hi) {
    return (unsigned)f2bf(lo) | ((unsigned)f2bf(hi) << 16);
}
// packed accumulate: 2 unpack + 1 v_pk_add_f32 per u32
__device__ __forceinline__ void accp(f32x2* a, uint4 v) {
    f32x2 t;
    t.x = bflo(v.x); t.y = bfhi(v.x); a[0] += t;
    t.x = bflo(v.y); t.y = bfhi(v.y); a[1] += t;
    t.x = bflo(v.z); t.y = bfhi(v.z); a[2] += t;
    t.x = bflo(v.w); t.y = bfhi(v.w); a[3] += t;
}

// ---------------- init: W transpose to bf16 ----------------
__global__ __launch_bounds__(256) void init_misc(const float* __restrict__ W1,
        const float* __restrict__ W2, unsigned short* __restrict__ Wt1,
        unsigned short* __restrict__ Wt2) {
    int t = blockIdx.x * 256 + threadIdx.x;
    if (t < 128 * 128) {
        int k = t >> 7, nn = t & 127;
        Wt1[nn * 128 + k] = f2bf(W1[t]);
    } else if (t < 128 * 128 + 128 * 64) {
        int i = t - 128 * 128;
        int k = i >> 6, nn = i & 63;
        Wt2[nn * 128 + k] = f2bf(W2[i]);
    }
}

// ---------------- phase 1: per-chunk bucket histogram ----------------
__global__ __launch_bounds__(256) void chunk_hist(const int* __restrict__ dst,
        int* __restrict__ ghist, int e, int nbuck) {
    __shared__ int cnt[MAXB];
    const int t = threadIdx.x;
    const int e0 = blockIdx.x * CHUNK;
    const int m = min(CHUNK, e - e0);
    for (int i = t; i < nbuck; i += 256) cnt[i] = 0;
    __syncthreads();
    for (int i = t; i < m; i += 256) atomicAdd(&cnt[dst[e0 + i] >> BSH], 1);
    __syncthreads();
    for (int i = t; i < nbuck; i += 256) ghist[blockIdx.x * nbuck + i] = cnt[i];
}

// ---------------- phase 2: per-bucket exclusive scan over chunks ----------------
// In-place: ghist[c][b] := b*CAP + prefix. bcur[b] := b*CAP + total.
__global__ __launch_bounds__(256) void chunk_scan(int* __restrict__ ghist,
        int* __restrict__ bcur, int nchunk, int nbuck) {
    __shared__ int wsum[4];
    const int t = threadIdx.x;
    const int b = blockIdx.x;
    const int lane = t & 63, wv = t >> 6;
    int carry = 0;
    for (int t0 = 0; t0 < nchunk; t0 += 256) {
        int c = t0 + t;
        int v = (c < nchunk) ? ghist[c * nbuck + b] : 0;
        int iv = v;
        for (int off = 1; off < 64; off <<= 1) {
            int u = __shfl_up(iv, off, 64);
            if (lane >= off) iv += u;
        }
        if (lane == 63) wsum[wv] = iv;
        __syncthreads();
        int woff = 0;
        for (int i = 0; i < wv; ++i) woff += wsum[i];
        int total = wsum[0] + wsum[1] + wsum[2] + wsum[3];
        int excl = iv - v + woff;
        if (c < nchunk) ghist[c * nbuck + b] = b * CAP + carry + excl;
        carry += total;
        __syncthreads();          // wsum reused next tile
    }
    if (t == 0) bcur[b] = b * CAP + carry;
}

// ---------------- phase 3: scatter to packed (LDS cursors, no global atomics) ---
// packed edge = (dstLocal << 22) | src   (src < 2^22, dstLocal < 512)
__global__ __launch_bounds__(256) void chunk_scatter(const int* __restrict__ src,
        const int* __restrict__ dst, const int* __restrict__ ghist,
        int* __restrict__ packed, int e, int nbuck) {
    __shared__ int cur[MAXB];
    const int t = threadIdx.x;
    const int e0 = blockIdx.x * CHUNK;
    const int m = min(CHUNK, e - e0);
    for (int i = t; i < nbuck; i += 256) cur[i] = ghist[blockIdx.x * nbuck + i];
    __syncthreads();
    for (int i = t; i < m; i += 256) {
        int d = dst[e0 + i], s = src[e0 + i];
        int b = d >> BSH;
        int p = atomicAdd(&cur[b], 1);
        if (p < (b + 1) * CAP)    // overflow guard (never expected)
            packed[p] = ((d & ((1 << BSH) - 1)) << 22) | s;
    }
}

// ---------------- per-bucket deg/roff/dinv/csr (512 nodes, 2 per thread) --------
__global__ __launch_bounds__(256) void bucket_build(const int* __restrict__ packed,
        const int* __restrict__ bcur, int* __restrict__ roff, int* __restrict__ degN,
        float* __restrict__ dinv, int* __restrict__ csr, int n) {
    __shared__ int deg[1 << BSH];
    __shared__ int cur[1 << BSH];
    __shared__ int wsum[4];
    const int t = threadIdx.x;
    const int b = blockIdx.x;
    const int nodeBase = b << BSH;
    const int nn = min(1 << BSH, n - nodeBase);
    const int e0 = b * CAP, e1 = bcur[b];

    for (int i = t; i < (1 << BSH); i += 256) deg[i] = 0;
    __syncthreads();
    for (int i = e0 + t; i < e1; i += 256)
        atomicAdd(&deg[(unsigned)packed[i] >> 22], 1);
    __syncthreads();

    const int i0 = t * 2;
    int d0 = deg[i0], d1 = deg[i0 + 1];
    int tsum = d0 + d1;
    int lane = t & 63, wv = t >> 6;
    int v = tsum;
    for (int off = 1; off < 64; off <<= 1) {
        int u = __shfl_up(v, off, 64);
        if (lane >= off) v += u;
    }
    if (lane == 63) wsum[wv] = v;
    __syncthreads();
    int woff = 0;
    for (int i = 0; i < wv; ++i) woff += wsum[i];
    int excl = v - tsum + woff;
    int p0 = excl, p1 = excl + d0;
    cur[i0] = p0; cur[i0 + 1] = p1;
    if (i0 < nn) {
        roff[nodeBase + i0] = e0 + p0;
        degN[nodeBase + i0] = d0;
        dinv[nodeBase + i0] = rsqrtf((float)(d0 + 1));
    }
    if (i0 + 1 < nn) {
        roff[nodeBase + i0 + 1] = e0 + p1;
        degN[nodeBase + i0 + 1] = d1;
        dinv[nodeBase + i0 + 1] = rsqrtf((float)(d1 + 1));
    }
    __syncthreads();

    for (int i = e0 + t; i < e1; i += 256) {
        unsigned pk = (unsigned)packed[i];
        int dl = pk >> 22;
        int s = pk & 0x3FFFFF;
        int slot = atomicAdd(&cur[dl], 1);
        csr[e0 + slot] = s;
    }
}

// ---------------- MFMA GEMM: out_bf[i][c] = bf16(dinv[i] * sum_k x[i][k]*W[k][c]) ----
// 64 rows x C cols per block, 4 waves. XBF: input already bf16.
template<int C, bool XBF>
__global__ __launch_bounds__(256) void gemm_mfma(const void* __restrict__ xv,
        const unsigned short* __restrict__ Wt, const float* __restrict__ dinv,
        unsigned short* __restrict__ out, int n)
{
    constexpr int KP = KD + 8;                 // 136 shorts = 272B row stride
    constexpr int WP = 64 + 8;                 // 72 shorts = 144B row stride
    __shared__ __align__(16) unsigned short xt[64 * KP];
    __shared__ __align__(16) unsigned short lw[C * WP];
    const int t = threadIdx.x;
    const int w = t >> 6, lane = t & 63;
    const int quad = lane >> 4, l16 = lane & 15;
    const int row0 = blockIdx.x * 64;

    // stage x tile (4 cols per iter)
    for (int i = t; i < 64 * 32; i += 256) {
        int r = i >> 5, c4 = (i & 31) * 4;
        int row = row0 + r;
        ushort4 pk = make_ushort4(0, 0, 0, 0);
        if (row < n) {
            if constexpr (XBF) {
                pk = *reinterpret_cast<const ushort4*>(
                    &((const unsigned short*)xv)[(size_t)row * KD + c4]);
            } else {
                float4 v = *reinterpret_cast<const float4*>(
                    &((const float*)xv)[(size_t)row * KD + c4]);
                pk.x = f2bf(v.x); pk.y = f2bf(v.y); pk.z = f2bf(v.z); pk.w = f2bf(v.w);
            }
        }
        *reinterpret_cast<ushort4*>(&xt[r * KP + c4]) = pk;
    }

    f32x4 acc[C / 16];
#pragma unroll
    for (int i = 0; i < C / 16; ++i) acc[i] = (f32x4)(0.f);

    for (int h = 0; h < 2; ++h) {
        __syncthreads();   // h=0: covers xt writes; h=1: waits for lw readers
        for (int i = t; i < C * 16; i += 256) {       // 8B chunks, 16 per Wt half-row
            int nr = i >> 4, j = (i & 15) * 4;
            *reinterpret_cast<ushort4*>(&lw[nr * WP + j]) =
                *reinterpret_cast<const ushort4*>(&Wt[nr * KD + h * 64 + j]);
        }
        __syncthreads();
#pragma unroll
        for (int kt = 0; kt < 2; ++kt) {
            bf16x8 af = *reinterpret_cast<const bf16x8*>(
                &xt[(w * 16 + l16) * KP + h * 64 + kt * 32 + quad * 8]);
#pragma unroll
            for (int ct = 0; ct < C / 16; ++ct) {
                bf16x8 bfr = *reinterpret_cast<const bf16x8*>(
                    &lw[(ct * 16 + l16) * WP + kt * 32 + quad * 8]);
                acc[ct] = __builtin_amdgcn_mfma_f32_16x16x32_bf16(af, bfr, acc[ct], 0, 0, 0);
            }
        }
    }

    // epilogue: D layout col = ct*16 + l16, row = quad*4 + j
#pragma unroll
    for (int j = 0; j < 4; ++j) {
        int row = row0 + w * 16 + quad * 4 + j;
        if (row < n) {
            float s = dinv[row];
#pragma unroll
            for (int ct = 0; ct < C / 16; ++ct)
                out[(size_t)row * C + ct * 16 + l16] = f2bf(acc[ct][j] * s);
        }
    }
}

// ---------------- gather128: quarter-wave dwordx4, 4 edges per load instr -------
// h1 row = 128 bf16 = 256B = 16 lanes x uint4. qw=lane>>4 handles edges j+qw,
// j+4+qw of each 8-block; quarters combined via shfl_xor(16|32).
// Node range [n0, n1): launched as two half dispatches (diagnostic + same perf).
__global__ __launch_bounds__(256) void gather128(const uint4* __restrict__ H,
        const int* __restrict__ roff, const int* __restrict__ degN,
        const int* __restrict__ csr, const float* __restrict__ dinv,
        const float* __restrict__ b, uint4* __restrict__ out, int n0, int n1)
{
    int wid = n0 + ((blockIdx.x * 256 + threadIdx.x) >> 6);
    int lane = threadIdx.x & 63;
    if (wid >= n1) return;
    const int qw = lane >> 4, cp = lane & 15;
    const char* Hb = (const char*)H;
    const unsigned cpo = (unsigned)cp * 16u;
    f32x2 a[4], c[4];
#pragma unroll
    for (int i = 0; i < 4; ++i) { a[i] = (f32x2)(0.f); c[i] = (f32x2)(0.f); }
    int e0 = roff[wid], e1 = e0 + degN[wid];
    for (int base = e0; base < e1; base += 64) {
        int m = e1 - base; if (m > 64) m = 64;
        int idx = (lane < m) ? csr[base + lane] : 0;
        int j = 0;
        for (; j + 8 <= m; j += 8) {
            unsigned u0 = (unsigned)__shfl(idx, j + qw);
            unsigned u1 = (unsigned)__shfl(idx, j + 4 + qw);
            uint4 v0 = *(const uint4*)(Hb + ((u0 << 8) + cpo));
            uint4 v1 = *(const uint4*)(Hb + ((u1 << 8) + cpo));
            accp(a, v0);
            accp(c, v1);
        }
        for (; j + 4 <= m; j += 4) {
            unsigned u = (unsigned)__shfl(idx, j + qw);
            uint4 v = *(const uint4*)(Hb + ((u << 8) + cpo));
            accp(a, v);
        }
        int r = m - j;
        if (r) {
            unsigned u = (unsigned)__shfl(idx, min(j + qw, m - 1));  // uniform-active shfl
            if (qw < r) {
                uint4 v = *(const uint4*)(Hb + ((u << 8) + cpo));
                accp(a, v);
            }
        }
    }
#pragma unroll
    for (int i = 0; i < 4; ++i) a[i] += c[i];
#pragma unroll
    for (int i = 0; i < 4; ++i) {
        a[i].x += __shfl_xor(a[i].x, 16, 64);
        a[i].x += __shfl_xor(a[i].x, 32, 64);
        a[i].y += __shfl_xor(a[i].y, 16, 64);
        a[i].y += __shfl_xor(a[i].y, 32, 64);
    }
    if (qw == 0) {
        uint4 sv = *(const uint4*)(Hb + (((unsigned)wid << 8) + cpo));  // self loop
        accp(a, sv);
        float s = dinv[wid];
        float4 b0 = ((const float4*)b)[cp * 2];
        float4 b1 = ((const float4*)b)[cp * 2 + 1];
        float r0 = fmaxf(s * a[0].x + b0.x, 0.f), r1 = fmaxf(s * a[0].y + b0.y, 0.f);
        float r2 = fmaxf(s * a[1].x + b0.z, 0.f), r3 = fmaxf(s * a[1].y + b0.w, 0.f);
        float r4 = fmaxf(s * a[2].x + b1.x, 0.f), r5 = fmaxf(s * a[2].y + b1.y, 0.f);
        float r6 = fmaxf(s * a[3].x + b1.z, 0.f), r7 = fmaxf(s * a[3].y + b1.w, 0.f);
        uint4 o;
        o.x = pk2(r0, r1); o.y = pk2(r2, r3); o.z = pk2(r4, r5); o.w = pk2(r6, r7);
        out[(size_t)wid * 16 + cp] = o;
    }
}

// ---------------- gather64: octave-wave dwordx4, 8 edges per load instr ---------
// h2 row = 64 bf16 = 128B = 8 lanes x uint4. oc=lane>>3 handles edge j+oc (and
// j+8+oc in the 16-block); octaves combined via shfl_xor(8|16|32).
__global__ __launch_bounds__(256) void gather64(const uint4* __restrict__ H,
        const int* __restrict__ roff, const int* __restrict__ degN,
        const int* __restrict__ csr, const float* __restrict__ dinv,
        const float* __restrict__ b, float4* __restrict__ out, int n)
{
    int wid = (blockIdx.x * 256 + threadIdx.x) >> 6;
    int lane = threadIdx.x & 63;
    if (wid >= n) return;
    const int oc = lane >> 3, cp = lane & 7;
    const char* Hb = (const char*)H;
    const unsigned cpo = (unsigned)cp * 16u;
    f32x2 a[4], c[4];
#pragma unroll
    for (int i = 0; i < 4; ++i) { a[i] = (f32x2)(0.f); c[i] = (f32x2)(0.f); }
    int e0 = roff[wid], e1 = e0 + degN[wid];
    for (int base = e0; base < e1; base += 64) {
        int m = e1 - base; if (m > 64) m = 64;
        int idx = (lane < m) ? csr[base + lane] : 0;
        int j = 0;
        for (; j + 16 <= m; j += 16) {
            unsigned u0 = (unsigned)__shfl(idx, j + oc);
            unsigned u1 = (unsigned)__shfl(idx, j + 8 + oc);
            uint4 v0 = *(const uint4*)(Hb + ((u0 << 7) + cpo));
            uint4 v1 = *(const uint4*)(Hb + ((u1 << 7) + cpo));
            accp(a, v0);
            accp(c, v1);
        }
        for (; j + 8 <= m; j += 8) {
            unsigned u = (unsigned)__shfl(idx, j + oc);
            uint4 v = *(const uint4*)(Hb + ((u << 7) + cpo));
            accp(a, v);
        }
        int r = m - j;
        if (r) {
            unsigned u = (unsigned)__shfl(idx, min(j + oc, m - 1));  // uniform-active shfl
            if (oc < r) {
                uint4 v = *(const uint4*)(Hb + ((u << 7) + cpo));
                accp(a, v);
            }
        }
    }
#pragma unroll
    for (int i = 0; i < 4; ++i) a[i] += c[i];
#pragma unroll
    for (int i = 0; i < 4; ++i) {
        a[i].x += __shfl_xor(a[i].x, 8, 64);
        a[i].x += __shfl_xor(a[i].x, 16, 64);
        a[i].x += __shfl_xor(a[i].x, 32, 64);
        a[i].y += __shfl_xor(a[i].y, 8, 64);
        a[i].y += __shfl_xor(a[i].y, 16, 64);
        a[i].y += __shfl_xor(a[i].y, 32, 64);
    }
    if (oc == 0) {
        uint4 sv = *(const uint4*)(Hb + (((unsigned)wid << 7) + cpo));  // self loop
        accp(a, sv);
        float s = dinv[wid];
        float4 b0 = ((const float4*)b)[cp * 2];
        float4 b1 = ((const float4*)b)[cp * 2 + 1];
        float4 o0 = make_float4(s * a[0].x + b0.x, s * a[0].y + b0.y,
                                s * a[1].x + b0.z, s * a[1].y + b0.w);
        float4 o1 = make_float4(s * a[2].x + b1.x, s * a[2].y + b1.y,
                                s * a[3].x + b1.z, s * a[3].y + b1.w);
        out[(size_t)wid * 16 + cp * 2] = o0;
        out[(size_t)wid * 16 + cp * 2 + 1] = o1;
    }
}

extern "C" void kernel_launch(void* const* d_in, const int* in_sizes, int n_in,
                              void* d_out, int out_size, void* d_ws, size_t ws_size,
                              hipStream_t stream)
{
    const int* ei = (const int*)d_in[0];
    const int E = in_sizes[0] / 2;
    const float* emb = (const float*)d_in[1];
    const int N = in_sizes[1] / KD;
    const float* W1 = (const float*)d_in[2];
    const float* b1 = (const float*)d_in[3];
    const float* W2 = (const float*)d_in[4];
    const float* b2 = (const float*)d_in[5];
    const int* src = ei;        // edge_index[0]
    const int* dst = ei + E;    // edge_index[1]
    const int nbuck = (N + (1 << BSH) - 1) >> BSH;   // 196 for N=100000
    const int nchunk = (E + CHUNK - 1) / CHUNK;      // 782

    // ---- workspace layout ----
    char* p = (char*)d_ws;
    auto alloc = [&](size_t bytes) { char* q = p; p += (bytes + 255) & ~(size_t)255; return q; };
    unsigned short* h1 = (unsigned short*)alloc((size_t)N * 128 * sizeof(unsigned short)); // bf16
    unsigned short* x2 = (unsigned short*)alloc((size_t)N * 128 * sizeof(unsigned short)); // bf16
    int*   csr    = (int*)  alloc((size_t)nbuck * CAP * sizeof(int));
    int*   packed = (int*)  alloc((size_t)nbuck * CAP * sizeof(int));
    int*   ghist  = (int*)  alloc((size_t)nchunk * nbuck * sizeof(int));
    int*   roff   = (int*)  alloc((size_t)N * sizeof(int));
    int*   degN   = (int*)  alloc((size_t)N * sizeof(int));
    float* dinv   = (float*)alloc((size_t)N * sizeof(float));
    int*   bcur   = (int*)  alloc(MAXB * sizeof(int));
    unsigned short* Wt1 = (unsigned short*)alloc(128 * 128 * sizeof(unsigned short));
    unsigned short* Wt2 = (unsigned short*)alloc(64 * 128 * sizeof(unsigned short));
    unsigned short* h2 = h1;                        // bf16 [N,64], h1 dead after gather128

    // ---- CSR build: atomic-free 3-phase partition + bucket_build ----
    init_misc<<<96, 256, 0, stream>>>(W1, W2, Wt1, Wt2);
    chunk_hist<<<nchunk, 256, 0, stream>>>(dst, ghist, E, nbuck);
    chunk_scan<<<nbuck, 256, 0, stream>>>(ghist, bcur, nchunk, nbuck);
    chunk_scatter<<<nchunk, 256, 0, stream>>>(src, dst, ghist, packed, E, nbuck);
    bucket_build<<<nbuck, 256, 0, stream>>>(packed, bcur, roff, degN, dinv, csr, N);

    // ---- layer 1 ----
    gemm_mfma<128, false><<<(N + 63) / 64, 256, 0, stream>>>(emb, Wt1, dinv, h1, N);
    const int half = ((N / 2) + 63) & ~63;          // 50048
    gather128<<<half / 4, 256, 0, stream>>>((const uint4*)h1, roff, degN, csr,
                                            dinv, b1, (uint4*)x2, 0, half);
    gather128<<<(N - half + 3) / 4, 256, 0, stream>>>((const uint4*)h1, roff, degN, csr,
                                                      dinv, b1, (uint4*)x2, half, N);

    // ---- layer 2 ----
    gemm_mfma<64, true><<<(N + 63) / 64, 256, 0, stream>>>(x2, Wt2, dinv, h2, N);
    gather64<<<(N + 3) / 4, 256, 0, stream>>>((const uint4*)h2, roff, degN, csr,
                                              dinv, b2, (float4*)d_out, N);
}

// Round 6
// 289.131 us; speedup vs baseline: 1.2036x; 1.0470x over previous
//
#include <hip/hip_runtime.h>
#include <hip/hip_bf16.h>
#include <stdint.h>

// GCN: out = Dinv (A+I) Dinv (X W) + b, two layers, relu between.
// N=100000, E=1600000, K=128, C1=128, C2=64. fp32 in/out (edge_index int32).
// R15: gather64 exposed at 45.9us: NOT at the 3.5TB/s fabric wall (2.0TB/s,
//   floor ~26us) -- half VALU-issue (~280 instr/wave, per-NODE overhead =~ edge
//   work at deg 16), half unhidden latency (2-load chain per node). Fix:
//   2 nodes per wave (32-lane halves, 4 octaves x 8 col-lanes each): same
//   8-edges-per-load-instr, but prologue/reduction(xor8,16 only)/self-loop/
//   epilogue shared by 2 nodes + 2 independent chains per wave.
//   Also: init_misc merged into chunk_hist (one launch fewer).
//   Kept: 3-phase atomic-free partition, quarter-wave gather128 (at mem floor,
//   split in 2 for top-5 visibility), pk_add f32x2, MFMA GEMMs, BSH=9.

static constexpr int KD = 128;
static constexpr int BSH = 9;                  // nodes per bucket = 512
static constexpr int MAXB = 256;               // max buckets supported
static constexpr int CHUNK = 2048;             // edges per partition chunk
static constexpr int CAP = 12288;              // bucket cap (mean 8163 + ~45 sigma)

typedef short bf16x8 __attribute__((ext_vector_type(8)));
typedef float f32x4  __attribute__((ext_vector_type(4)));
typedef float f32x2  __attribute__((ext_vector_type(2)));

__device__ __forceinline__ unsigned short f2bf(float f) {
    __hip_bfloat16 b = __float2bfloat16(f);    // RNE
    return *reinterpret_cast<unsigned short*>(&b);
}
__device__ __forceinline__ float bflo(unsigned v) { return __uint_as_float(v << 16); }
__device__ __forceinline__ float bfhi(unsigned v) { return __uint_as_float(v & 0xffff0000u); }
__device__ __forceinline__ unsigned pk2(float lo, float hi) {
    return (unsigned)f2bf(lo) | ((unsigned)f2bf(hi) << 16);
}
// packed accumulate: 2 unpack + 1 v_pk_add_f32 per u32
__device__ __forceinline__ void accp(f32x2* a, uint4 v) {
    f32x2 t;
    t.x = bflo(v.x); t.y = bfhi(v.x); a[0] += t;
    t.x = bflo(v.y); t.y = bfhi(v.y); a[1] += t;
    t.x = bflo(v.z); t.y = bfhi(v.z); a[2] += t;
    t.x = bflo(v.w); t.y = bfhi(v.w); a[3] += t;
}

// ------- phase 1: per-chunk bucket histogram (+ W transpose on blocks <96) ------
__global__ __launch_bounds__(256) void init_hist(const float* __restrict__ W1,
        const float* __restrict__ W2, unsigned short* __restrict__ Wt1,
        unsigned short* __restrict__ Wt2, const int* __restrict__ dst,
        int* __restrict__ ghist, int e, int nbuck) {
    __shared__ int cnt[MAXB];
    const int t = threadIdx.x;
    const int e0 = blockIdx.x * CHUNK;
    const int m = min(CHUNK, e - e0);
    for (int i = t; i < nbuck; i += 256) cnt[i] = 0;
    __syncthreads();
    for (int i = t; i < m; i += 256) atomicAdd(&cnt[dst[e0 + i] >> BSH], 1);
    // W transpose piggyback: 96 blocks x 256 = 24576 = 128*128 + 128*64 exactly
    int g = blockIdx.x * 256 + t;
    if (g < 128 * 128) {
        int k = g >> 7, nn = g & 127;
        Wt1[nn * 128 + k] = f2bf(W1[g]);
    } else if (g < 128 * 128 + 128 * 64) {
        int i = g - 128 * 128;
        int k = i >> 6, nn = i & 63;
        Wt2[nn * 128 + k] = f2bf(W2[i]);
    }
    __syncthreads();
    for (int i = t; i < nbuck; i += 256) ghist[blockIdx.x * nbuck + i] = cnt[i];
}

// ---------------- phase 2: per-bucket exclusive scan over chunks ----------------
// In-place: ghist[c][b] := b*CAP + prefix. bcur[b] := b*CAP + total.
__global__ __launch_bounds__(256) void chunk_scan(int* __restrict__ ghist,
        int* __restrict__ bcur, int nchunk, int nbuck) {
    __shared__ int wsum[4];
    const int t = threadIdx.x;
    const int b = blockIdx.x;
    const int lane = t & 63, wv = t >> 6;
    int carry = 0;
    for (int t0 = 0; t0 < nchunk; t0 += 256) {
        int c = t0 + t;
        int v = (c < nchunk) ? ghist[c * nbuck + b] : 0;
        int iv = v;
        for (int off = 1; off < 64; off <<= 1) {
            int u = __shfl_up(iv, off, 64);
            if (lane >= off) iv += u;
        }
        if (lane == 63) wsum[wv] = iv;
        __syncthreads();
        int woff = 0;
        for (int i = 0; i < wv; ++i) woff += wsum[i];
        int total = wsum[0] + wsum[1] + wsum[2] + wsum[3];
        int excl = iv - v + woff;
        if (c < nchunk) ghist[c * nbuck + b] = b * CAP + carry + excl;
        carry += total;
        __syncthreads();          // wsum reused next tile
    }
    if (t == 0) bcur[b] = b * CAP + carry;
}

// ---------------- phase 3: scatter to packed (LDS cursors, no global atomics) ---
// packed edge = (dstLocal << 22) | src   (src < 2^22, dstLocal < 512)
__global__ __launch_bounds__(256) void chunk_scatter(const int* __restrict__ src,
        const int* __restrict__ dst, const int* __restrict__ ghist,
        int* __restrict__ packed, int e, int nbuck) {
    __shared__ int cur[MAXB];
    const int t = threadIdx.x;
    const int e0 = blockIdx.x * CHUNK;
    const int m = min(CHUNK, e - e0);
    for (int i = t; i < nbuck; i += 256) cur[i] = ghist[blockIdx.x * nbuck + i];
    __syncthreads();
    for (int i = t; i < m; i += 256) {
        int d = dst[e0 + i], s = src[e0 + i];
        int b = d >> BSH;
        int p = atomicAdd(&cur[b], 1);
        if (p < (b + 1) * CAP)    // overflow guard (never expected)
            packed[p] = ((d & ((1 << BSH) - 1)) << 22) | s;
    }
}

// ---------------- per-bucket deg/roff/dinv/csr (512 nodes, 2 per thread) --------
__global__ __launch_bounds__(256) void bucket_build(const int* __restrict__ packed,
        const int* __restrict__ bcur, int* __restrict__ roff, int* __restrict__ degN,
        float* __restrict__ dinv, int* __restrict__ csr, int n) {
    __shared__ int deg[1 << BSH];
    __shared__ int cur[1 << BSH];
    __shared__ int wsum[4];
    const int t = threadIdx.x;
    const int b = blockIdx.x;
    const int nodeBase = b << BSH;
    const int nn = min(1 << BSH, n - nodeBase);
    const int e0 = b * CAP, e1 = bcur[b];

    for (int i = t; i < (1 << BSH); i += 256) deg[i] = 0;
    __syncthreads();
    for (int i = e0 + t; i < e1; i += 256)
        atomicAdd(&deg[(unsigned)packed[i] >> 22], 1);
    __syncthreads();

    const int i0 = t * 2;
    int d0 = deg[i0], d1 = deg[i0 + 1];
    int tsum = d0 + d1;
    int lane = t & 63, wv = t >> 6;
    int v = tsum;
    for (int off = 1; off < 64; off <<= 1) {
        int u = __shfl_up(v, off, 64);
        if (lane >= off) v += u;
    }
    if (lane == 63) wsum[wv] = v;
    __syncthreads();
    int woff = 0;
    for (int i = 0; i < wv; ++i) woff += wsum[i];
    int excl = v - tsum + woff;
    int p0 = excl, p1 = excl + d0;
    cur[i0] = p0; cur[i0 + 1] = p1;
    if (i0 < nn) {
        roff[nodeBase + i0] = e0 + p0;
        degN[nodeBase + i0] = d0;
        dinv[nodeBase + i0] = rsqrtf((float)(d0 + 1));
    }
    if (i0 + 1 < nn) {
        roff[nodeBase + i0 + 1] = e0 + p1;
        degN[nodeBase + i0 + 1] = d1;
        dinv[nodeBase + i0 + 1] = rsqrtf((float)(d1 + 1));
    }
    __syncthreads();

    for (int i = e0 + t; i < e1; i += 256) {
        unsigned pk = (unsigned)packed[i];
        int dl = pk >> 22;
        int s = pk & 0x3FFFFF;
        int slot = atomicAdd(&cur[dl], 1);
        csr[e0 + slot] = s;
    }
}

// ---------------- MFMA GEMM: out_bf[i][c] = bf16(dinv[i] * sum_k x[i][k]*W[k][c]) ----
// 64 rows x C cols per block, 4 waves. XBF: input already bf16.
template<int C, bool XBF>
__global__ __launch_bounds__(256) void gemm_mfma(const void* __restrict__ xv,
        const unsigned short* __restrict__ Wt, const float* __restrict__ dinv,
        unsigned short* __restrict__ out, int n)
{
    constexpr int KP = KD + 8;                 // 136 shorts = 272B row stride
    constexpr int WP = 64 + 8;                 // 72 shorts = 144B row stride
    __shared__ __align__(16) unsigned short xt[64 * KP];
    __shared__ __align__(16) unsigned short lw[C * WP];
    const int t = threadIdx.x;
    const int w = t >> 6, lane = t & 63;
    const int quad = lane >> 4, l16 = lane & 15;
    const int row0 = blockIdx.x * 64;

    // stage x tile (4 cols per iter)
    for (int i = t; i < 64 * 32; i += 256) {
        int r = i >> 5, c4 = (i & 31) * 4;
        int row = row0 + r;
        ushort4 pk = make_ushort4(0, 0, 0, 0);
        if (row < n) {
            if constexpr (XBF) {
                pk = *reinterpret_cast<const ushort4*>(
                    &((const unsigned short*)xv)[(size_t)row * KD + c4]);
            } else {
                float4 v = *reinterpret_cast<const float4*>(
                    &((const float*)xv)[(size_t)row * KD + c4]);
                pk.x = f2bf(v.x); pk.y = f2bf(v.y); pk.z = f2bf(v.z); pk.w = f2bf(v.w);
            }
        }
        *reinterpret_cast<ushort4*>(&xt[r * KP + c4]) = pk;
    }

    f32x4 acc[C / 16];
#pragma unroll
    for (int i = 0; i < C / 16; ++i) acc[i] = (f32x4)(0.f);

    for (int h = 0; h < 2; ++h) {
        __syncthreads();   // h=0: covers xt writes; h=1: waits for lw readers
        for (int i = t; i < C * 16; i += 256) {       // 8B chunks, 16 per Wt half-row
            int nr = i >> 4, j = (i & 15) * 4;
            *reinterpret_cast<ushort4*>(&lw[nr * WP + j]) =
                *reinterpret_cast<const ushort4*>(&Wt[nr * KD + h * 64 + j]);
        }
        __syncthreads();
#pragma unroll
        for (int kt = 0; kt < 2; ++kt) {
            bf16x8 af = *reinterpret_cast<const bf16x8*>(
                &xt[(w * 16 + l16) * KP + h * 64 + kt * 32 + quad * 8]);
#pragma unroll
            for (int ct = 0; ct < C / 16; ++ct) {
                bf16x8 bfr = *reinterpret_cast<const bf16x8*>(
                    &lw[(ct * 16 + l16) * WP + kt * 32 + quad * 8]);
                acc[ct] = __builtin_amdgcn_mfma_f32_16x16x32_bf16(af, bfr, acc[ct], 0, 0, 0);
            }
        }
    }

    // epilogue: D layout col = ct*16 + l16, row = quad*4 + j
#pragma unroll
    for (int j = 0; j < 4; ++j) {
        int row = row0 + w * 16 + quad * 4 + j;
        if (row < n) {
            float s = dinv[row];
#pragma unroll
            for (int ct = 0; ct < C / 16; ++ct)
                out[(size_t)row * C + ct * 16 + l16] = f2bf(acc[ct][j] * s);
        }
    }
}

// ---------------- gather128: quarter-wave dwordx4, 4 edges per load instr -------
// h1 row = 128 bf16 = 256B = 16 lanes x uint4. qw=lane>>4 handles edges j+qw,
// j+4+qw of each 8-block; quarters combined via shfl_xor(16|32).
// Node range [n0, n1): launched as two half dispatches (top-5 visibility).
__global__ __launch_bounds__(256) void gather128(const uint4* __restrict__ H,
        const int* __restrict__ roff, const int* __restrict__ degN,
        const int* __restrict__ csr, const float* __restrict__ dinv,
        const float* __restrict__ b, uint4* __restrict__ out, int n0, int n1)
{
    int wid = n0 + ((blockIdx.x * 256 + threadIdx.x) >> 6);
    int lane = threadIdx.x & 63;
    if (wid >= n1) return;
    const int qw = lane >> 4, cp = lane & 15;
    const char* Hb = (const char*)H;
    const unsigned cpo = (unsigned)cp * 16u;
    f32x2 a[4], c[4];
#pragma unroll
    for (int i = 0; i < 4; ++i) { a[i] = (f32x2)(0.f); c[i] = (f32x2)(0.f); }
    int e0 = roff[wid], e1 = e0 + degN[wid];
    for (int base = e0; base < e1; base += 64) {
        int m = e1 - base; if (m > 64) m = 64;
        int idx = (lane < m) ? csr[base + lane] : 0;
        int j = 0;
        for (; j + 8 <= m; j += 8) {
            unsigned u0 = (unsigned)__shfl(idx, j + qw);
            unsigned u1 = (unsigned)__shfl(idx, j + 4 + qw);
            uint4 v0 = *(const uint4*)(Hb + ((u0 << 8) + cpo));
            uint4 v1 = *(const uint4*)(Hb + ((u1 << 8) + cpo));
            accp(a, v0);
            accp(c, v1);
        }
        for (; j + 4 <= m; j += 4) {
            unsigned u = (unsigned)__shfl(idx, j + qw);
            uint4 v = *(const uint4*)(Hb + ((u << 8) + cpo));
            accp(a, v);
        }
        int r = m - j;
        if (r) {
            unsigned u = (unsigned)__shfl(idx, min(j + qw, m - 1));  // uniform-active shfl
            if (qw < r) {
                uint4 v = *(const uint4*)(Hb + ((u << 8) + cpo));
                accp(a, v);
            }
        }
    }
#pragma unroll
    for (int i = 0; i < 4; ++i) a[i] += c[i];
#pragma unroll
    for (int i = 0; i < 4; ++i) {
        a[i].x += __shfl_xor(a[i].x, 16, 64);
        a[i].x += __shfl_xor(a[i].x, 32, 64);
        a[i].y += __shfl_xor(a[i].y, 16, 64);
        a[i].y += __shfl_xor(a[i].y, 32, 64);
    }
    if (qw == 0) {
        uint4 sv = *(const uint4*)(Hb + (((unsigned)wid << 8) + cpo));  // self loop
        accp(a, sv);
        float s = dinv[wid];
        float4 b0 = ((const float4*)b)[cp * 2];
        float4 b1 = ((const float4*)b)[cp * 2 + 1];
        float r0 = fmaxf(s * a[0].x + b0.x, 0.f), r1 = fmaxf(s * a[0].y + b0.y, 0.f);
        float r2 = fmaxf(s * a[1].x + b0.z, 0.f), r3 = fmaxf(s * a[1].y + b0.w, 0.f);
        float r4 = fmaxf(s * a[2].x + b1.x, 0.f), r5 = fmaxf(s * a[2].y + b1.y, 0.f);
        float r6 = fmaxf(s * a[3].x + b1.z, 0.f), r7 = fmaxf(s * a[3].y + b1.w, 0.f);
        uint4 o;
        o.x = pk2(r0, r1); o.y = pk2(r2, r3); o.z = pk2(r4, r5); o.w = pk2(r6, r7);
        out[(size_t)wid * 16 + cp] = o;
    }
}

// ---------------- gather64: 2 nodes per wave (32-lane halves) -------------------
// h2 row = 64 bf16 = 128B = 8 lanes x uint4. half=lane>>5 owns node 2*wpair+half;
// oc=(lane>>3)&3 covers edges j+oc, j+4+oc within the half; octaves combined via
// shfl_xor(8|16) (within-half). m uniform per half -> divergence only between
// halves; all shfl sources stay inside the active half.
__global__ __launch_bounds__(256) void gather64(const uint4* __restrict__ H,
        const int* __restrict__ roff, const int* __restrict__ degN,
        const int* __restrict__ csr, const float* __restrict__ dinv,
        const float* __restrict__ b, float4* __restrict__ out, int n)
{
    int wpair = (blockIdx.x * 256 + threadIdx.x) >> 6;
    int lane = threadIdx.x & 63;
    const int half = lane >> 5, h32 = half << 5;
    const int oc = (lane >> 3) & 3, cp = lane & 7;
    const int l32 = lane & 31;
    const int node = wpair * 2 + half;
    const char* Hb = (const char*)H;
    const unsigned cpo = (unsigned)cp * 16u;
    f32x2 a[4], c[4];
#pragma unroll
    for (int i = 0; i < 4; ++i) { a[i] = (f32x2)(0.f); c[i] = (f32x2)(0.f); }
    int e0 = 0, deg = 0;
    if (node < n) { e0 = roff[node]; deg = degN[node]; }
    for (int base = 0; base < deg; base += 32) {
        int m = deg - base; if (m > 32) m = 32;
        int idx = (l32 < m) ? csr[e0 + base + l32] : 0;
        int j = 0;
        for (; j + 8 <= m; j += 8) {
            unsigned u0 = (unsigned)__shfl(idx, h32 + j + oc, 64);
            unsigned u1 = (unsigned)__shfl(idx, h32 + j + 4 + oc, 64);
            uint4 v0 = *(const uint4*)(Hb + ((u0 << 7) + cpo));
            uint4 v1 = *(const uint4*)(Hb + ((u1 << 7) + cpo));
            accp(a, v0);
            accp(c, v1);
        }
        for (; j + 4 <= m; j += 4) {
            unsigned u = (unsigned)__shfl(idx, h32 + j + oc, 64);
            uint4 v = *(const uint4*)(Hb + ((u << 7) + cpo));
            accp(a, v);
        }
        int r = m - j;                          // 0..3
        if (r) {
            unsigned u = (unsigned)__shfl(idx, h32 + min(j + oc, m - 1), 64);
            if (oc < r) {
                uint4 v = *(const uint4*)(Hb + ((u << 7) + cpo));
                accp(a, v);
            }
        }
    }
#pragma unroll
    for (int i = 0; i < 4; ++i) a[i] += c[i];
#pragma unroll
    for (int i = 0; i < 4; ++i) {               // within-half reduce (octaves 0..3)
        a[i].x += __shfl_xor(a[i].x, 8, 64);
        a[i].x += __shfl_xor(a[i].x, 16, 64);
        a[i].y += __shfl_xor(a[i].y, 8, 64);
        a[i].y += __shfl_xor(a[i].y, 16, 64);
    }
    if (oc == 0 && node < n) {
        uint4 sv = *(const uint4*)(Hb + (((unsigned)node << 7) + cpo));  // self loop
        accp(a, sv);
        float s = dinv[node];
        float4 b0 = ((const float4*)b)[cp * 2];
        float4 b1 = ((const float4*)b)[cp * 2 + 1];
        float4 o0 = make_float4(s * a[0].x + b0.x, s * a[0].y + b0.y,
                                s * a[1].x + b0.z, s * a[1].y + b0.w);
        float4 o1 = make_float4(s * a[2].x + b1.x, s * a[2].y + b1.y,
                                s * a[3].x + b1.z, s * a[3].y + b1.w);
        out[(size_t)node * 16 + cp * 2] = o0;
        out[(size_t)node * 16 + cp * 2 + 1] = o1;
    }
}

extern "C" void kernel_launch(void* const* d_in, const int* in_sizes, int n_in,
                              void* d_out, int out_size, void* d_ws, size_t ws_size,
                              hipStream_t stream)
{
    const int* ei = (const int*)d_in[0];
    const int E = in_sizes[0] / 2;
    const float* emb = (const float*)d_in[1];
    const int N = in_sizes[1] / KD;
    const float* W1 = (const float*)d_in[2];
    const float* b1 = (const float*)d_in[3];
    const float* W2 = (const float*)d_in[4];
    const float* b2 = (const float*)d_in[5];
    const int* src = ei;        // edge_index[0]
    const int* dst = ei + E;    // edge_index[1]
    const int nbuck = (N + (1 << BSH) - 1) >> BSH;   // 196 for N=100000
    const int nchunk = (E + CHUNK - 1) / CHUNK;      // 782

    // ---- workspace layout ----
    char* p = (char*)d_ws;
    auto alloc = [&](size_t bytes) { char* q = p; p += (bytes + 255) & ~(size_t)255; return q; };
    unsigned short* h1 = (unsigned short*)alloc((size_t)N * 128 * sizeof(unsigned short)); // bf16
    unsigned short* x2 = (unsigned short*)alloc((size_t)N * 128 * sizeof(unsigned short)); // bf16
    int*   csr    = (int*)  alloc((size_t)nbuck * CAP * sizeof(int));
    int*   packed = (int*)  alloc((size_t)nbuck * CAP * sizeof(int));
    int*   ghist  = (int*)  alloc((size_t)nchunk * nbuck * sizeof(int));
    int*   roff   = (int*)  alloc((size_t)N * sizeof(int));
    int*   degN   = (int*)  alloc((size_t)N * sizeof(int));
    float* dinv   = (float*)alloc((size_t)N * sizeof(float));
    int*   bcur   = (int*)  alloc(MAXB * sizeof(int));
    unsigned short* Wt1 = (unsigned short*)alloc(128 * 128 * sizeof(unsigned short));
    unsigned short* Wt2 = (unsigned short*)alloc(64 * 128 * sizeof(unsigned short));
    unsigned short* h2 = h1;                        // bf16 [N,64], h1 dead after gather128

    // ---- CSR build: atomic-free 3-phase partition + bucket_build ----
    init_hist<<<nchunk, 256, 0, stream>>>(W1, W2, Wt1, Wt2, dst, ghist, E, nbuck);
    chunk_scan<<<nbuck, 256, 0, stream>>>(ghist, bcur, nchunk, nbuck);
    chunk_scatter<<<nchunk, 256, 0, stream>>>(src, dst, ghist, packed, E, nbuck);
    bucket_build<<<nbuck, 256, 0, stream>>>(packed, bcur, roff, degN, dinv, csr, N);

    // ---- layer 1 ----
    gemm_mfma<128, false><<<(N + 63) / 64, 256, 0, stream>>>(emb, Wt1, dinv, h1, N);
    const int half = ((N / 2) + 63) & ~63;          // 50048
    gather128<<<half / 4, 256, 0, stream>>>((const uint4*)h1, roff, degN, csr,
                                            dinv, b1, (uint4*)x2, 0, half);
    gather128<<<(N - half + 3) / 4, 256, 0, stream>>>((const uint4*)h1, roff, degN, csr,
                                                      dinv, b1, (uint4*)x2, half, N);

    // ---- layer 2 ----
    gemm_mfma<64, true><<<(N + 63) / 64, 256, 0, stream>>>(x2, Wt2, dinv, h2, N);
    gather64<<<(N + 7) / 8, 256, 0, stream>>>((const uint4*)h2, roff, degN, csr,
                                              dinv, b2, (float4*)d_out, N);
}

// Round 7
// 286.856 us; speedup vs baseline: 1.2132x; 1.0079x over previous
//
#include <hip/hip_runtime.h>
#include <hip/hip_bf16.h>
#include <stdint.h>

// GCN: out = Dinv (A+I) Dinv (X W) + b, two layers, relu between.
// N=100000, E=1600000, K=128, C1=128, C2=64. fp32 in/out (edge_index int32).
// R16: top-5 now fill-clogged (harness 256MiB poison @41us); all our kernels
//   <40us. Largest modeled middle kernel = bucket_build (196 blocks = 0.77/CU,
//   2 serial passes). Fix: BSH 9->8 (392 buckets of 256 nodes): 2x blocks for
//   bucket_build+chunk_scan, half serial work/block, 1 node/thread, less LDS
//   counter contention in hist/scatter. packed = (dstLocal<<24)|src (src<2^24).
//   gather128 merged back to one dispatch (split diagnostic no longer visible).
//   Kept: 3-phase atomic-free partition, quarter-wave gather128 (mem floor),
//   2-node/wave gather64, pk_add f32x2, 32-bit saddr offsets, MFMA GEMMs.

static constexpr int KD = 128;
static constexpr int BSH = 8;                  // nodes per bucket = 256
static constexpr int MAXB = 512;               // max buckets supported
static constexpr int CHUNK = 2048;             // edges per partition chunk
static constexpr int CAP = 6144;               // bucket cap (mean 4092 + ~32 sigma)

typedef short bf16x8 __attribute__((ext_vector_type(8)));
typedef float f32x4  __attribute__((ext_vector_type(4)));
typedef float f32x2  __attribute__((ext_vector_type(2)));

__device__ __forceinline__ unsigned short f2bf(float f) {
    __hip_bfloat16 b = __float2bfloat16(f);    // RNE
    return *reinterpret_cast<unsigned short*>(&b);
}
__device__ __forceinline__ float bflo(unsigned v) { return __uint_as_float(v << 16); }
__device__ __forceinline__ float bfhi(unsigned v) { return __uint_as_float(v & 0xffff0000u); }
__device__ __forceinline__ unsigned pk2(float lo, float hi) {
    return (unsigned)f2bf(lo) | ((unsigned)f2bf(hi) << 16);
}
// packed accumulate: 2 unpack + 1 v_pk_add_f32 per u32
__device__ __forceinline__ void accp(f32x2* a, uint4 v) {
    f32x2 t;
    t.x = bflo(v.x); t.y = bfhi(v.x); a[0] += t;
    t.x = bflo(v.y); t.y = bfhi(v.y); a[1] += t;
    t.x = bflo(v.z); t.y = bfhi(v.z); a[2] += t;
    t.x = bflo(v.w); t.y = bfhi(v.w); a[3] += t;
}

// ------- phase 1: per-chunk bucket histogram (+ W transpose on blocks <96) ------
__global__ __launch_bounds__(256) void init_hist(const float* __restrict__ W1,
        const float* __restrict__ W2, unsigned short* __restrict__ Wt1,
        unsigned short* __restrict__ Wt2, const int* __restrict__ dst,
        int* __restrict__ ghist, int e, int nbuck) {
    __shared__ int cnt[MAXB];
    const int t = threadIdx.x;
    const int e0 = blockIdx.x * CHUNK;
    const int m = min(CHUNK, e - e0);
    for (int i = t; i < nbuck; i += 256) cnt[i] = 0;
    __syncthreads();
    for (int i = t; i < m; i += 256) atomicAdd(&cnt[dst[e0 + i] >> BSH], 1);
    // W transpose piggyback: 96 blocks x 256 = 24576 = 128*128 + 128*64 exactly
    int g = blockIdx.x * 256 + t;
    if (g < 128 * 128) {
        int k = g >> 7, nn = g & 127;
        Wt1[nn * 128 + k] = f2bf(W1[g]);
    } else if (g < 128 * 128 + 128 * 64) {
        int i = g - 128 * 128;
        int k = i >> 6, nn = i & 63;
        Wt2[nn * 128 + k] = f2bf(W2[i]);
    }
    __syncthreads();
    for (int i = t; i < nbuck; i += 256) ghist[blockIdx.x * nbuck + i] = cnt[i];
}

// ---------------- phase 2: per-bucket exclusive scan over chunks ----------------
// In-place: ghist[c][b] := b*CAP + prefix. bcur[b] := b*CAP + total.
__global__ __launch_bounds__(256) void chunk_scan(int* __restrict__ ghist,
        int* __restrict__ bcur, int nchunk, int nbuck) {
    __shared__ int wsum[4];
    const int t = threadIdx.x;
    const int b = blockIdx.x;
    const int lane = t & 63, wv = t >> 6;
    int carry = 0;
    for (int t0 = 0; t0 < nchunk; t0 += 256) {
        int c = t0 + t;
        int v = (c < nchunk) ? ghist[c * nbuck + b] : 0;
        int iv = v;
        for (int off = 1; off < 64; off <<= 1) {
            int u = __shfl_up(iv, off, 64);
            if (lane >= off) iv += u;
        }
        if (lane == 63) wsum[wv] = iv;
        __syncthreads();
        int woff = 0;
        for (int i = 0; i < wv; ++i) woff += wsum[i];
        int total = wsum[0] + wsum[1] + wsum[2] + wsum[3];
        int excl = iv - v + woff;
        if (c < nchunk) ghist[c * nbuck + b] = b * CAP + carry + excl;
        carry += total;
        __syncthreads();          // wsum reused next tile
    }
    if (t == 0) bcur[b] = b * CAP + carry;
}

// ---------------- phase 3: scatter to packed (LDS cursors, no global atomics) ---
// packed edge = (dstLocal << 24) | src   (src < 2^24, dstLocal < 256)
__global__ __launch_bounds__(256) void chunk_scatter(const int* __restrict__ src,
        const int* __restrict__ dst, const int* __restrict__ ghist,
        int* __restrict__ packed, int e, int nbuck) {
    __shared__ int cur[MAXB];
    const int t = threadIdx.x;
    const int e0 = blockIdx.x * CHUNK;
    const int m = min(CHUNK, e - e0);
    for (int i = t; i < nbuck; i += 256) cur[i] = ghist[blockIdx.x * nbuck + i];
    __syncthreads();
    for (int i = t; i < m; i += 256) {
        int d = dst[e0 + i], s = src[e0 + i];
        int b = d >> BSH;
        int p = atomicAdd(&cur[b], 1);
        if (p < (b + 1) * CAP)    // overflow guard (never expected)
            packed[p] = ((d & ((1 << BSH) - 1)) << 24) | s;
    }
}

// ------------ per-bucket deg/roff/dinv/csr (256 nodes, 1 per thread) ------------
__global__ __launch_bounds__(256) void bucket_build(const int* __restrict__ packed,
        const int* __restrict__ bcur, int* __restrict__ roff, int* __restrict__ degN,
        float* __restrict__ dinv, int* __restrict__ csr, int n) {
    __shared__ int deg[1 << BSH];
    __shared__ int cur[1 << BSH];
    __shared__ int wsum[4];
    const int t = threadIdx.x;
    const int b = blockIdx.x;
    const int nodeBase = b << BSH;
    const int nn = min(1 << BSH, n - nodeBase);
    const int e0 = b * CAP, e1 = bcur[b];

    deg[t] = 0;
    __syncthreads();
    for (int i = e0 + t; i < e1; i += 256)
        atomicAdd(&deg[(unsigned)packed[i] >> 24], 1);
    __syncthreads();

    const int d = deg[t];
    int lane = t & 63, wv = t >> 6;
    int iv = d;
    for (int off = 1; off < 64; off <<= 1) {
        int u = __shfl_up(iv, off, 64);
        if (lane >= off) iv += u;
    }
    if (lane == 63) wsum[wv] = iv;
    __syncthreads();
    int woff = 0;
    for (int i = 0; i < wv; ++i) woff += wsum[i];
    int excl = iv - d + woff;
    cur[t] = excl;
    if (t < nn) {
        roff[nodeBase + t] = e0 + excl;
        degN[nodeBase + t] = d;
        dinv[nodeBase + t] = rsqrtf((float)(d + 1));
    }
    __syncthreads();

    for (int i = e0 + t; i < e1; i += 256) {
        unsigned pk = (unsigned)packed[i];
        int dl = pk >> 24;
        int s = pk & 0xFFFFFF;
        int slot = atomicAdd(&cur[dl], 1);
        csr[e0 + slot] = s;
    }
}

// ---------------- MFMA GEMM: out_bf[i][c] = bf16(dinv[i] * sum_k x[i][k]*W[k][c]) ----
// 64 rows x C cols per block, 4 waves. XBF: input already bf16.
template<int C, bool XBF>
__global__ __launch_bounds__(256) void gemm_mfma(const void* __restrict__ xv,
        const unsigned short* __restrict__ Wt, const float* __restrict__ dinv,
        unsigned short* __restrict__ out, int n)
{
    constexpr int KP = KD + 8;                 // 136 shorts = 272B row stride
    constexpr int WP = 64 + 8;                 // 72 shorts = 144B row stride
    __shared__ __align__(16) unsigned short xt[64 * KP];
    __shared__ __align__(16) unsigned short lw[C * WP];
    const int t = threadIdx.x;
    const int w = t >> 6, lane = t & 63;
    const int quad = lane >> 4, l16 = lane & 15;
    const int row0 = blockIdx.x * 64;

    // stage x tile (4 cols per iter)
    for (int i = t; i < 64 * 32; i += 256) {
        int r = i >> 5, c4 = (i & 31) * 4;
        int row = row0 + r;
        ushort4 pk = make_ushort4(0, 0, 0, 0);
        if (row < n) {
            if constexpr (XBF) {
                pk = *reinterpret_cast<const ushort4*>(
                    &((const unsigned short*)xv)[(size_t)row * KD + c4]);
            } else {
                float4 v = *reinterpret_cast<const float4*>(
                    &((const float*)xv)[(size_t)row * KD + c4]);
                pk.x = f2bf(v.x); pk.y = f2bf(v.y); pk.z = f2bf(v.z); pk.w = f2bf(v.w);
            }
        }
        *reinterpret_cast<ushort4*>(&xt[r * KP + c4]) = pk;
    }

    f32x4 acc[C / 16];
#pragma unroll
    for (int i = 0; i < C / 16; ++i) acc[i] = (f32x4)(0.f);

    for (int h = 0; h < 2; ++h) {
        __syncthreads();   // h=0: covers xt writes; h=1: waits for lw readers
        for (int i = t; i < C * 16; i += 256) {       // 8B chunks, 16 per Wt half-row
            int nr = i >> 4, j = (i & 15) * 4;
            *reinterpret_cast<ushort4*>(&lw[nr * WP + j]) =
                *reinterpret_cast<const ushort4*>(&Wt[nr * KD + h * 64 + j]);
        }
        __syncthreads();
#pragma unroll
        for (int kt = 0; kt < 2; ++kt) {
            bf16x8 af = *reinterpret_cast<const bf16x8*>(
                &xt[(w * 16 + l16) * KP + h * 64 + kt * 32 + quad * 8]);
#pragma unroll
            for (int ct = 0; ct < C / 16; ++ct) {
                bf16x8 bfr = *reinterpret_cast<const bf16x8*>(
                    &lw[(ct * 16 + l16) * WP + kt * 32 + quad * 8]);
                acc[ct] = __builtin_amdgcn_mfma_f32_16x16x32_bf16(af, bfr, acc[ct], 0, 0, 0);
            }
        }
    }

    // epilogue: D layout col = ct*16 + l16, row = quad*4 + j
#pragma unroll
    for (int j = 0; j < 4; ++j) {
        int row = row0 + w * 16 + quad * 4 + j;
        if (row < n) {
            float s = dinv[row];
#pragma unroll
            for (int ct = 0; ct < C / 16; ++ct)
                out[(size_t)row * C + ct * 16 + l16] = f2bf(acc[ct][j] * s);
        }
    }
}

// ---------------- gather128: quarter-wave dwordx4, 4 edges per load instr -------
// h1 row = 128 bf16 = 256B = 16 lanes x uint4. qw=lane>>4 handles edges j+qw,
// j+4+qw of each 8-block; quarters combined via shfl_xor(16|32).
__global__ __launch_bounds__(256) void gather128(const uint4* __restrict__ H,
        const int* __restrict__ roff, const int* __restrict__ degN,
        const int* __restrict__ csr, const float* __restrict__ dinv,
        const float* __restrict__ b, uint4* __restrict__ out, int n)
{
    int wid = (blockIdx.x * 256 + threadIdx.x) >> 6;
    int lane = threadIdx.x & 63;
    if (wid >= n) return;
    const int qw = lane >> 4, cp = lane & 15;
    const char* Hb = (const char*)H;
    const unsigned cpo = (unsigned)cp * 16u;
    f32x2 a[4], c[4];
#pragma unroll
    for (int i = 0; i < 4; ++i) { a[i] = (f32x2)(0.f); c[i] = (f32x2)(0.f); }
    int e0 = roff[wid], e1 = e0 + degN[wid];
    for (int base = e0; base < e1; base += 64) {
        int m = e1 - base; if (m > 64) m = 64;
        int idx = (lane < m) ? csr[base + lane] : 0;
        int j = 0;
        for (; j + 8 <= m; j += 8) {
            unsigned u0 = (unsigned)__shfl(idx, j + qw);
            unsigned u1 = (unsigned)__shfl(idx, j + 4 + qw);
            uint4 v0 = *(const uint4*)(Hb + ((u0 << 8) + cpo));
            uint4 v1 = *(const uint4*)(Hb + ((u1 << 8) + cpo));
            accp(a, v0);
            accp(c, v1);
        }
        for (; j + 4 <= m; j += 4) {
            unsigned u = (unsigned)__shfl(idx, j + qw);
            uint4 v = *(const uint4*)(Hb + ((u << 8) + cpo));
            accp(a, v);
        }
        int r = m - j;
        if (r) {
            unsigned u = (unsigned)__shfl(idx, min(j + qw, m - 1));  // uniform-active shfl
            if (qw < r) {
                uint4 v = *(const uint4*)(Hb + ((u << 8) + cpo));
                accp(a, v);
            }
        }
    }
#pragma unroll
    for (int i = 0; i < 4; ++i) a[i] += c[i];
#pragma unroll
    for (int i = 0; i < 4; ++i) {
        a[i].x += __shfl_xor(a[i].x, 16, 64);
        a[i].x += __shfl_xor(a[i].x, 32, 64);
        a[i].y += __shfl_xor(a[i].y, 16, 64);
        a[i].y += __shfl_xor(a[i].y, 32, 64);
    }
    if (qw == 0) {
        uint4 sv = *(const uint4*)(Hb + (((unsigned)wid << 8) + cpo));  // self loop
        accp(a, sv);
        float s = dinv[wid];
        float4 b0 = ((const float4*)b)[cp * 2];
        float4 b1 = ((const float4*)b)[cp * 2 + 1];
        float r0 = fmaxf(s * a[0].x + b0.x, 0.f), r1 = fmaxf(s * a[0].y + b0.y, 0.f);
        float r2 = fmaxf(s * a[1].x + b0.z, 0.f), r3 = fmaxf(s * a[1].y + b0.w, 0.f);
        float r4 = fmaxf(s * a[2].x + b1.x, 0.f), r5 = fmaxf(s * a[2].y + b1.y, 0.f);
        float r6 = fmaxf(s * a[3].x + b1.z, 0.f), r7 = fmaxf(s * a[3].y + b1.w, 0.f);
        uint4 o;
        o.x = pk2(r0, r1); o.y = pk2(r2, r3); o.z = pk2(r4, r5); o.w = pk2(r6, r7);
        out[(size_t)wid * 16 + cp] = o;
    }
}

// ---------------- gather64: 2 nodes per wave (32-lane halves) -------------------
// h2 row = 64 bf16 = 128B = 8 lanes x uint4. half=lane>>5 owns node 2*wpair+half;
// oc=(lane>>3)&3 covers edges j+oc, j+4+oc within the half; octaves combined via
// shfl_xor(8|16) (within-half).
__global__ __launch_bounds__(256) void gather64(const uint4* __restrict__ H,
        const int* __restrict__ roff, const int* __restrict__ degN,
        const int* __restrict__ csr, const float* __restrict__ dinv,
        const float* __restrict__ b, float4* __restrict__ out, int n)
{
    int wpair = (blockIdx.x * 256 + threadIdx.x) >> 6;
    int lane = threadIdx.x & 63;
    const int half = lane >> 5, h32 = half << 5;
    const int oc = (lane >> 3) & 3, cp = lane & 7;
    const int l32 = lane & 31;
    const int node = wpair * 2 + half;
    const char* Hb = (const char*)H;
    const unsigned cpo = (unsigned)cp * 16u;
    f32x2 a[4], c[4];
#pragma unroll
    for (int i = 0; i < 4; ++i) { a[i] = (f32x2)(0.f); c[i] = (f32x2)(0.f); }
    int e0 = 0, deg = 0;
    if (node < n) { e0 = roff[node]; deg = degN[node]; }
    for (int base = 0; base < deg; base += 32) {
        int m = deg - base; if (m > 32) m = 32;
        int idx = (l32 < m) ? csr[e0 + base + l32] : 0;
        int j = 0;
        for (; j + 8 <= m; j += 8) {
            unsigned u0 = (unsigned)__shfl(idx, h32 + j + oc, 64);
            unsigned u1 = (unsigned)__shfl(idx, h32 + j + 4 + oc, 64);
            uint4 v0 = *(const uint4*)(Hb + ((u0 << 7) + cpo));
            uint4 v1 = *(const uint4*)(Hb + ((u1 << 7) + cpo));
            accp(a, v0);
            accp(c, v1);
        }
        for (; j + 4 <= m; j += 4) {
            unsigned u = (unsigned)__shfl(idx, h32 + j + oc, 64);
            uint4 v = *(const uint4*)(Hb + ((u << 7) + cpo));
            accp(a, v);
        }
        int r = m - j;                          // 0..3
        if (r) {
            unsigned u = (unsigned)__shfl(idx, h32 + min(j + oc, m - 1), 64);
            if (oc < r) {
                uint4 v = *(const uint4*)(Hb + ((u << 7) + cpo));
                accp(a, v);
            }
        }
    }
#pragma unroll
    for (int i = 0; i < 4; ++i) a[i] += c[i];
#pragma unroll
    for (int i = 0; i < 4; ++i) {               // within-half reduce (octaves 0..3)
        a[i].x += __shfl_xor(a[i].x, 8, 64);
        a[i].x += __shfl_xor(a[i].x, 16, 64);
        a[i].y += __shfl_xor(a[i].y, 8, 64);
        a[i].y += __shfl_xor(a[i].y, 16, 64);
    }
    if (oc == 0 && node < n) {
        uint4 sv = *(const uint4*)(Hb + (((unsigned)node << 7) + cpo));  // self loop
        accp(a, sv);
        float s = dinv[node];
        float4 b0 = ((const float4*)b)[cp * 2];
        float4 b1 = ((const float4*)b)[cp * 2 + 1];
        float4 o0 = make_float4(s * a[0].x + b0.x, s * a[0].y + b0.y,
                                s * a[1].x + b0.z, s * a[1].y + b0.w);
        float4 o1 = make_float4(s * a[2].x + b1.x, s * a[2].y + b1.y,
                                s * a[3].x + b1.z, s * a[3].y + b1.w);
        out[(size_t)node * 16 + cp * 2] = o0;
        out[(size_t)node * 16 + cp * 2 + 1] = o1;
    }
}

extern "C" void kernel_launch(void* const* d_in, const int* in_sizes, int n_in,
                              void* d_out, int out_size, void* d_ws, size_t ws_size,
                              hipStream_t stream)
{
    const int* ei = (const int*)d_in[0];
    const int E = in_sizes[0] / 2;
    const float* emb = (const float*)d_in[1];
    const int N = in_sizes[1] / KD;
    const float* W1 = (const float*)d_in[2];
    const float* b1 = (const float*)d_in[3];
    const float* W2 = (const float*)d_in[4];
    const float* b2 = (const float*)d_in[5];
    const int* src = ei;        // edge_index[0]
    const int* dst = ei + E;    // edge_index[1]
    const int nbuck = (N + (1 << BSH) - 1) >> BSH;   // 391 for N=100000
    const int nchunk = (E + CHUNK - 1) / CHUNK;      // 782

    // ---- workspace layout ----
    char* p = (char*)d_ws;
    auto alloc = [&](size_t bytes) { char* q = p; p += (bytes + 255) & ~(size_t)255; return q; };
    unsigned short* h1 = (unsigned short*)alloc((size_t)N * 128 * sizeof(unsigned short)); // bf16
    unsigned short* x2 = (unsigned short*)alloc((size_t)N * 128 * sizeof(unsigned short)); // bf16
    int*   csr    = (int*)  alloc((size_t)nbuck * CAP * sizeof(int));
    int*   packed = (int*)  alloc((size_t)nbuck * CAP * sizeof(int));
    int*   ghist  = (int*)  alloc((size_t)nchunk * nbuck * sizeof(int));
    int*   roff   = (int*)  alloc((size_t)N * sizeof(int));
    int*   degN   = (int*)  alloc((size_t)N * sizeof(int));
    float* dinv   = (float*)alloc((size_t)N * sizeof(float));
    int*   bcur   = (int*)  alloc(MAXB * sizeof(int));
    unsigned short* Wt1 = (unsigned short*)alloc(128 * 128 * sizeof(unsigned short));
    unsigned short* Wt2 = (unsigned short*)alloc(64 * 128 * sizeof(unsigned short));
    unsigned short* h2 = h1;                        // bf16 [N,64], h1 dead after gather128

    // ---- CSR build: atomic-free 3-phase partition + bucket_build ----
    init_hist<<<nchunk, 256, 0, stream>>>(W1, W2, Wt1, Wt2, dst, ghist, E, nbuck);
    chunk_scan<<<nbuck, 256, 0, stream>>>(ghist, bcur, nchunk, nbuck);
    chunk_scatter<<<nchunk, 256, 0, stream>>>(src, dst, ghist, packed, E, nbuck);
    bucket_build<<<nbuck, 256, 0, stream>>>(packed, bcur, roff, degN, dinv, csr, N);

    // ---- layer 1 ----
    gemm_mfma<128, false><<<(N + 63) / 64, 256, 0, stream>>>(emb, Wt1, dinv, h1, N);
    gather128<<<(N + 3) / 4, 256, 0, stream>>>((const uint4*)h1, roff, degN, csr,
                                               dinv, b1, (uint4*)x2, N);

    // ---- layer 2 ----
    gemm_mfma<64, true><<<(N + 63) / 64, 256, 0, stream>>>(x2, Wt2, dinv, h2, N);
    gather64<<<(N + 7) / 8, 256, 0, stream>>>((const uint4*)h2, roff, degN, csr,
                                              dinv, b2, (float4*)d_out, N);
}

// Round 8
// 279.273 us; speedup vs baseline: 1.2461x; 1.0272x over previous
//
#include <hip/hip_runtime.h>
#include <hip/hip_bf16.h>
#include <stdint.h>

// GCN: out = Dinv (A+I) Dinv (X W) + b, two layers, relu between.
// N=100000, E=1600000, K=128, C1=128, C2=64. fp32 in/out (edge_index int32).
// R17: ~135us of the 287 is harness ws-poison fills (fixed); our kernels ~150us.
//   Attacks: (1) h1 = RAW emb@W1 (no dinv) -> per-edge dinv fma in gather128
//   (pk_add->pk_fma, same VALU; dinv L2-resident, +3MB FETCH only) which frees
//   gemm128 from the bucket_build dependency; (2) gemm128 fused into
//   chunk_scatter (role-split blocks) to hide the latency-bound scatter;
//   (3) gather64 4 nodes/wave (16-lane quarters, xor8 reduce only).
//   Kept: 3-phase atomic-free partition BSH=8, quarter-wave gather128 (at the
//   3.5TB/s fabric wall), pk f32x2 math, 32-bit saddr offsets, MFMA GEMMs.

static constexpr int KD = 128;
static constexpr int BSH = 8;                  // nodes per bucket = 256
static constexpr int MAXB = 512;               // max buckets supported
static constexpr int CHUNK = 2048;             // edges per partition chunk
static constexpr int CAP = 6144;               // bucket cap (mean 4092 + ~32 sigma)

typedef short bf16x8 __attribute__((ext_vector_type(8)));
typedef float f32x4  __attribute__((ext_vector_type(4)));
typedef float f32x2  __attribute__((ext_vector_type(2)));

__device__ __forceinline__ unsigned short f2bf(float f) {
    __hip_bfloat16 b = __float2bfloat16(f);    // RNE
    return *reinterpret_cast<unsigned short*>(&b);
}
__device__ __forceinline__ float bflo(unsigned v) { return __uint_as_float(v << 16); }
__device__ __forceinline__ float bfhi(unsigned v) { return __uint_as_float(v & 0xffff0000u); }
__device__ __forceinline__ unsigned pk2(float lo, float hi) {
    return (unsigned)f2bf(lo) | ((unsigned)f2bf(hi) << 16);
}
// packed accumulate: 2 unpack + 1 v_pk_add_f32 per u32
__device__ __forceinline__ void accp(f32x2* a, uint4 v) {
    f32x2 t;
    t.x = bflo(v.x); t.y = bfhi(v.x); a[0] += t;
    t.x = bflo(v.y); t.y = bfhi(v.y); a[1] += t;
    t.x = bflo(v.z); t.y = bfhi(v.z); a[2] += t;
    t.x = bflo(v.w); t.y = bfhi(v.w); a[3] += t;
}
// packed fma accumulate: a += d * unpack(v)  (pk_fma, same instr count as accp)
__device__ __forceinline__ void accf(f32x2* a, uint4 v, float d) {
    f32x2 dd; dd.x = d; dd.y = d;
    f32x2 t;
    t.x = bflo(v.x); t.y = bfhi(v.x); a[0] += dd * t;
    t.x = bflo(v.y); t.y = bfhi(v.y); a[1] += dd * t;
    t.x = bflo(v.z); t.y = bfhi(v.z); a[2] += dd * t;
    t.x = bflo(v.w); t.y = bfhi(v.w); a[3] += dd * t;
}

// ------- phase 1: per-chunk bucket histogram (+ W transpose on blocks <96) ------
__global__ __launch_bounds__(256) void init_hist(const float* __restrict__ W1,
        const float* __restrict__ W2, unsigned short* __restrict__ Wt1,
        unsigned short* __restrict__ Wt2, const int* __restrict__ dst,
        int* __restrict__ ghist, int e, int nbuck) {
    __shared__ int cnt[MAXB];
    const int t = threadIdx.x;
    const int e0 = blockIdx.x * CHUNK;
    const int m = min(CHUNK, e - e0);
    for (int i = t; i < nbuck; i += 256) cnt[i] = 0;
    __syncthreads();
    for (int i = t; i < m; i += 256) atomicAdd(&cnt[dst[e0 + i] >> BSH], 1);
    // W transpose piggyback: 96 blocks x 256 = 24576 = 128*128 + 128*64 exactly
    int g = blockIdx.x * 256 + t;
    if (g < 128 * 128) {
        int k = g >> 7, nn = g & 127;
        Wt1[nn * 128 + k] = f2bf(W1[g]);
    } else if (g < 128 * 128 + 128 * 64) {
        int i = g - 128 * 128;
        int k = i >> 6, nn = i & 63;
        Wt2[nn * 128 + k] = f2bf(W2[i]);
    }
    __syncthreads();
    for (int i = t; i < nbuck; i += 256) ghist[blockIdx.x * nbuck + i] = cnt[i];
}

// ---------------- phase 2: per-bucket exclusive scan over chunks ----------------
// In-place: ghist[c][b] := b*CAP + prefix. bcur[b] := b*CAP + total.
__global__ __launch_bounds__(256) void chunk_scan(int* __restrict__ ghist,
        int* __restrict__ bcur, int nchunk, int nbuck) {
    __shared__ int wsum[4];
    const int t = threadIdx.x;
    const int b = blockIdx.x;
    const int lane = t & 63, wv = t >> 6;
    int carry = 0;
    for (int t0 = 0; t0 < nchunk; t0 += 256) {
        int c = t0 + t;
        int v = (c < nchunk) ? ghist[c * nbuck + b] : 0;
        int iv = v;
        for (int off = 1; off < 64; off <<= 1) {
            int u = __shfl_up(iv, off, 64);
            if (lane >= off) iv += u;
        }
        if (lane == 63) wsum[wv] = iv;
        __syncthreads();
        int woff = 0;
        for (int i = 0; i < wv; ++i) woff += wsum[i];
        int total = wsum[0] + wsum[1] + wsum[2] + wsum[3];
        int excl = iv - v + woff;
        if (c < nchunk) ghist[c * nbuck + b] = b * CAP + carry + excl;
        carry += total;
        __syncthreads();          // wsum reused next tile
    }
    if (t == 0) bcur[b] = b * CAP + carry;
}

// ------- phase 3 + layer1 matmul fused (role-split blocks, independent work) ----
// blocks [0,nscatter): scatter to packed (LDS cursors, no global atomics)
//   packed edge = (dstLocal << 24) | src   (src < 2^24, dstLocal < 256)
// blocks [nscatter,...): h1[i][c] = bf16(sum_k emb[i][k] W1[k][c])  (RAW, no dinv)
__global__ __launch_bounds__(256) void scatter_gemm(const int* __restrict__ src,
        const int* __restrict__ dst, const int* __restrict__ ghist,
        int* __restrict__ packed, int e, int nbuck, int nscatter,
        const float* __restrict__ xv, const unsigned short* __restrict__ Wt,
        unsigned short* __restrict__ out, int n)
{
    constexpr int C = 128;
    constexpr int KP = KD + 8;                 // 136 shorts = 272B row stride
    constexpr int WP = 64 + 8;                 // 72 shorts = 144B row stride
    __shared__ __align__(16) unsigned short xt[64 * KP];
    __shared__ __align__(16) unsigned short lw[C * WP];
    __shared__ int cur[MAXB];
    const int t = threadIdx.x;

    if (blockIdx.x < nscatter) {               // ---- scatter role ----
        const int e0 = blockIdx.x * CHUNK;
        const int m = min(CHUNK, e - e0);
        for (int i = t; i < nbuck; i += 256) cur[i] = ghist[blockIdx.x * nbuck + i];
        __syncthreads();
        for (int i = t; i < m; i += 256) {
            int d = dst[e0 + i], s = src[e0 + i];
            int b = d >> BSH;
            int p = atomicAdd(&cur[b], 1);
            if (p < (b + 1) * CAP)             // overflow guard (never expected)
                packed[p] = ((d & ((1 << BSH) - 1)) << 24) | s;
        }
        return;
    }

    // ---- gemm role (C=128, fp32 input, raw output) ----
    const int w = t >> 6, lane = t & 63;
    const int quad = lane >> 4, l16 = lane & 15;
    const int row0 = (blockIdx.x - nscatter) * 64;

    for (int i = t; i < 64 * 32; i += 256) {
        int r = i >> 5, c4 = (i & 31) * 4;
        int row = row0 + r;
        ushort4 pk = make_ushort4(0, 0, 0, 0);
        if (row < n) {
            float4 v = *reinterpret_cast<const float4*>(&xv[(size_t)row * KD + c4]);
            pk.x = f2bf(v.x); pk.y = f2bf(v.y); pk.z = f2bf(v.z); pk.w = f2bf(v.w);
        }
        *reinterpret_cast<ushort4*>(&xt[r * KP + c4]) = pk;
    }

    f32x4 acc[C / 16];
#pragma unroll
    for (int i = 0; i < C / 16; ++i) acc[i] = (f32x4)(0.f);

    for (int h = 0; h < 2; ++h) {
        __syncthreads();
        for (int i = t; i < C * 16; i += 256) {
            int nr = i >> 4, j = (i & 15) * 4;
            *reinterpret_cast<ushort4*>(&lw[nr * WP + j]) =
                *reinterpret_cast<const ushort4*>(&Wt[nr * KD + h * 64 + j]);
        }
        __syncthreads();
#pragma unroll
        for (int kt = 0; kt < 2; ++kt) {
            bf16x8 af = *reinterpret_cast<const bf16x8*>(
                &xt[(w * 16 + l16) * KP + h * 64 + kt * 32 + quad * 8]);
#pragma unroll
            for (int ct = 0; ct < C / 16; ++ct) {
                bf16x8 bfr = *reinterpret_cast<const bf16x8*>(
                    &lw[(ct * 16 + l16) * WP + kt * 32 + quad * 8]);
                acc[ct] = __builtin_amdgcn_mfma_f32_16x16x32_bf16(af, bfr, acc[ct], 0, 0, 0);
            }
        }
    }
#pragma unroll
    for (int j = 0; j < 4; ++j) {
        int row = row0 + w * 16 + quad * 4 + j;
        if (row < n) {
#pragma unroll
            for (int ct = 0; ct < C / 16; ++ct)
                out[(size_t)row * C + ct * 16 + l16] = f2bf(acc[ct][j]);
        }
    }
}

// ------------ per-bucket deg/roff/dinv/csr (256 nodes, 1 per thread) ------------
__global__ __launch_bounds__(256) void bucket_build(const int* __restrict__ packed,
        const int* __restrict__ bcur, int* __restrict__ roff, int* __restrict__ degN,
        float* __restrict__ dinv, int* __restrict__ csr, int n) {
    __shared__ int deg[1 << BSH];
    __shared__ int cur[1 << BSH];
    __shared__ int wsum[4];
    const int t = threadIdx.x;
    const int b = blockIdx.x;
    const int nodeBase = b << BSH;
    const int nn = min(1 << BSH, n - nodeBase);
    const int e0 = b * CAP, e1 = bcur[b];

    deg[t] = 0;
    __syncthreads();
    for (int i = e0 + t; i < e1; i += 256)
        atomicAdd(&deg[(unsigned)packed[i] >> 24], 1);
    __syncthreads();

    const int d = deg[t];
    int lane = t & 63, wv = t >> 6;
    int iv = d;
    for (int off = 1; off < 64; off <<= 1) {
        int u = __shfl_up(iv, off, 64);
        if (lane >= off) iv += u;
    }
    if (lane == 63) wsum[wv] = iv;
    __syncthreads();
    int woff = 0;
    for (int i = 0; i < wv; ++i) woff += wsum[i];
    int excl = iv - d + woff;
    cur[t] = excl;
    if (t < nn) {
        roff[nodeBase + t] = e0 + excl;
        degN[nodeBase + t] = d;
        dinv[nodeBase + t] = rsqrtf((float)(d + 1));
    }
    __syncthreads();

    for (int i = e0 + t; i < e1; i += 256) {
        unsigned pk = (unsigned)packed[i];
        int dl = pk >> 24;
        int s = pk & 0xFFFFFF;
        int slot = atomicAdd(&cur[dl], 1);
        csr[e0 + slot] = s;
    }
}

// ------- MFMA GEMM layer2: h2[i][c] = bf16(dinv[i] * sum_k x2[i][k] W2[k][c]) ----
__global__ __launch_bounds__(256) void gemm_mfma64(const unsigned short* __restrict__ xv,
        const unsigned short* __restrict__ Wt, const float* __restrict__ dinv,
        unsigned short* __restrict__ out, int n)
{
    constexpr int C = 64;
    constexpr int KP = KD + 8;
    constexpr int WP = 64 + 8;
    __shared__ __align__(16) unsigned short xt[64 * KP];
    __shared__ __align__(16) unsigned short lw[C * WP];
    const int t = threadIdx.x;
    const int w = t >> 6, lane = t & 63;
    const int quad = lane >> 4, l16 = lane & 15;
    const int row0 = blockIdx.x * 64;

    for (int i = t; i < 64 * 32; i += 256) {
        int r = i >> 5, c4 = (i & 31) * 4;
        int row = row0 + r;
        ushort4 pk = make_ushort4(0, 0, 0, 0);
        if (row < n)
            pk = *reinterpret_cast<const ushort4*>(&xv[(size_t)row * KD + c4]);
        *reinterpret_cast<ushort4*>(&xt[r * KP + c4]) = pk;
    }

    f32x4 acc[C / 16];
#pragma unroll
    for (int i = 0; i < C / 16; ++i) acc[i] = (f32x4)(0.f);

    for (int h = 0; h < 2; ++h) {
        __syncthreads();
        for (int i = t; i < C * 16; i += 256) {
            int nr = i >> 4, j = (i & 15) * 4;
            *reinterpret_cast<ushort4*>(&lw[nr * WP + j]) =
                *reinterpret_cast<const ushort4*>(&Wt[nr * KD + h * 64 + j]);
        }
        __syncthreads();
#pragma unroll
        for (int kt = 0; kt < 2; ++kt) {
            bf16x8 af = *reinterpret_cast<const bf16x8*>(
                &xt[(w * 16 + l16) * KP + h * 64 + kt * 32 + quad * 8]);
#pragma unroll
            for (int ct = 0; ct < C / 16; ++ct) {
                bf16x8 bfr = *reinterpret_cast<const bf16x8*>(
                    &lw[(ct * 16 + l16) * WP + kt * 32 + quad * 8]);
                acc[ct] = __builtin_amdgcn_mfma_f32_16x16x32_bf16(af, bfr, acc[ct], 0, 0, 0);
            }
        }
    }
#pragma unroll
    for (int j = 0; j < 4; ++j) {
        int row = row0 + w * 16 + quad * 4 + j;
        if (row < n) {
            float s = dinv[row];
#pragma unroll
            for (int ct = 0; ct < C / 16; ++ct)
                out[(size_t)row * C + ct * 16 + l16] = f2bf(acc[ct][j] * s);
        }
    }
}

// ---------------- gather128: quarter-wave dwordx4 + per-edge dinv fma -----------
// h1 row = 128 bf16 = 256B = 16 lanes x uint4 (RAW emb@W1). qw=lane>>4 handles
// edges j+qw, j+4+qw; x2[d] = relu(dinv_d*(sum_s dinv_s*h[s] + dinv_d*h[d]) + b).
__global__ __launch_bounds__(256) void gather128(const uint4* __restrict__ H,
        const int* __restrict__ roff, const int* __restrict__ degN,
        const int* __restrict__ csr, const float* __restrict__ dinv,
        const float* __restrict__ b, uint4* __restrict__ out, int n)
{
    int wid = (blockIdx.x * 256 + threadIdx.x) >> 6;
    int lane = threadIdx.x & 63;
    if (wid >= n) return;
    const int qw = lane >> 4, cp = lane & 15;
    const char* Hb = (const char*)H;
    const unsigned cpo = (unsigned)cp * 16u;
    f32x2 a[4], c[4];
#pragma unroll
    for (int i = 0; i < 4; ++i) { a[i] = (f32x2)(0.f); c[i] = (f32x2)(0.f); }
    int e0 = roff[wid], e1 = e0 + degN[wid];
    for (int base = e0; base < e1; base += 64) {
        int m = e1 - base; if (m > 64) m = 64;
        int idx = (lane < m) ? csr[base + lane] : 0;
        int j = 0;
        for (; j + 8 <= m; j += 8) {
            unsigned u0 = (unsigned)__shfl(idx, j + qw);
            unsigned u1 = (unsigned)__shfl(idx, j + 4 + qw);
            float d0 = dinv[u0], d1 = dinv[u1];
            uint4 v0 = *(const uint4*)(Hb + ((u0 << 8) + cpo));
            uint4 v1 = *(const uint4*)(Hb + ((u1 << 8) + cpo));
            accf(a, v0, d0);
            accf(c, v1, d1);
        }
        for (; j + 4 <= m; j += 4) {
            unsigned u = (unsigned)__shfl(idx, j + qw);
            float d0 = dinv[u];
            uint4 v = *(const uint4*)(Hb + ((u << 8) + cpo));
            accf(a, v, d0);
        }
        int r = m - j;
        if (r) {
            unsigned u = (unsigned)__shfl(idx, min(j + qw, m - 1));  // uniform-active shfl
            if (qw < r) {
                float d0 = dinv[u];
                uint4 v = *(const uint4*)(Hb + ((u << 8) + cpo));
                accf(a, v, d0);
            }
        }
    }
#pragma unroll
    for (int i = 0; i < 4; ++i) a[i] += c[i];
#pragma unroll
    for (int i = 0; i < 4; ++i) {
        a[i].x += __shfl_xor(a[i].x, 16, 64);
        a[i].x += __shfl_xor(a[i].x, 32, 64);
        a[i].y += __shfl_xor(a[i].y, 16, 64);
        a[i].y += __shfl_xor(a[i].y, 32, 64);
    }
    if (qw == 0) {
        float s = dinv[wid];
        uint4 sv = *(const uint4*)(Hb + (((unsigned)wid << 8) + cpo));  // self loop
        accf(a, sv, s);                         // a += dinv_d * h[d]
        float4 b0 = ((const float4*)b)[cp * 2];
        float4 b1 = ((const float4*)b)[cp * 2 + 1];
        float r0 = fmaxf(s * a[0].x + b0.x, 0.f), r1 = fmaxf(s * a[0].y + b0.y, 0.f);
        float r2 = fmaxf(s * a[1].x + b0.z, 0.f), r3 = fmaxf(s * a[1].y + b0.w, 0.f);
        float r4 = fmaxf(s * a[2].x + b1.x, 0.f), r5 = fmaxf(s * a[2].y + b1.y, 0.f);
        float r6 = fmaxf(s * a[3].x + b1.z, 0.f), r7 = fmaxf(s * a[3].y + b1.w, 0.f);
        uint4 o;
        o.x = pk2(r0, r1); o.y = pk2(r2, r3); o.z = pk2(r4, r5); o.w = pk2(r6, r7);
        out[(size_t)wid * 16 + cp] = o;
    }
}

// ---------------- gather64: 4 nodes per wave (16-lane quarters) -----------------
// h2 row = 64 bf16 = 128B = 8 lanes x uint4. quarter q=lane>>4 owns node
// 4*wquad+q; oc=(lane>>3)&1 covers edges j+oc; reduce = single shfl_xor(8).
__global__ __launch_bounds__(256) void gather64(const uint4* __restrict__ H,
        const int* __restrict__ roff, const int* __restrict__ degN,
        const int* __restrict__ csr, const float* __restrict__ dinv,
        const float* __restrict__ b, float4* __restrict__ out, int n)
{
    int wquad = (blockIdx.x * 256 + threadIdx.x) >> 6;
    int lane = threadIdx.x & 63;
    const int q16 = lane & 48;                 // quarter base (0,16,32,48)
    const int l16 = lane & 15;
    const int oc = l16 >> 3, cp = lane & 7;
    const int node = wquad * 4 + (q16 >> 4);
    const char* Hb = (const char*)H;
    const unsigned cpo = (unsigned)cp * 16u;
    f32x2 a[4], c[4];
#pragma unroll
    for (int i = 0; i < 4; ++i) { a[i] = (f32x2)(0.f); c[i] = (f32x2)(0.f); }
    int e0 = 0, deg = 0;
    if (node < n) { e0 = roff[node]; deg = degN[node]; }
    for (int base = 0; base < deg; base += 16) {
        int m = deg - base; if (m > 16) m = 16;
        int idx = (l16 < m) ? csr[e0 + base + l16] : 0;
        int j = 0;
        for (; j + 4 <= m; j += 4) {
            unsigned u0 = (unsigned)__shfl(idx, q16 + j + oc, 64);
            unsigned u1 = (unsigned)__shfl(idx, q16 + j + 2 + oc, 64);
            uint4 v0 = *(const uint4*)(Hb + ((u0 << 7) + cpo));
            uint4 v1 = *(const uint4*)(Hb + ((u1 << 7) + cpo));
            accp(a, v0);
            accp(c, v1);
        }
        for (; j + 2 <= m; j += 2) {
            unsigned u = (unsigned)__shfl(idx, q16 + j + oc, 64);
            uint4 v = *(const uint4*)(Hb + ((u << 7) + cpo));
            accp(a, v);
        }
        if (j < m) {                            // r == 1 -> oc 0 only
            unsigned u = (unsigned)__shfl(idx, q16 + m - 1, 64);
            if (oc == 0) {
                uint4 v = *(const uint4*)(Hb + ((u << 7) + cpo));
                accp(a, v);
            }
        }
    }
#pragma unroll
    for (int i = 0; i < 4; ++i) a[i] += c[i];
#pragma unroll
    for (int i = 0; i < 4; ++i) {               // combine oc pair (within quarter)
        a[i].x += __shfl_xor(a[i].x, 8, 64);
        a[i].y += __shfl_xor(a[i].y, 8, 64);
    }
    if (oc == 0 && node < n) {
        uint4 sv = *(const uint4*)(Hb + (((unsigned)node << 7) + cpo));  // self loop
        accp(a, sv);
        float s = dinv[node];
        float4 b0 = ((const float4*)b)[cp * 2];
        float4 b1 = ((const float4*)b)[cp * 2 + 1];
        float4 o0 = make_float4(s * a[0].x + b0.x, s * a[0].y + b0.y,
                                s * a[1].x + b0.z, s * a[1].y + b0.w);
        float4 o1 = make_float4(s * a[2].x + b1.x, s * a[2].y + b1.y,
                                s * a[3].x + b1.z, s * a[3].y + b1.w);
        out[(size_t)node * 16 + cp * 2] = o0;
        out[(size_t)node * 16 + cp * 2 + 1] = o1;
    }
}

extern "C" void kernel_launch(void* const* d_in, const int* in_sizes, int n_in,
                              void* d_out, int out_size, void* d_ws, size_t ws_size,
                              hipStream_t stream)
{
    const int* ei = (const int*)d_in[0];
    const int E = in_sizes[0] / 2;
    const float* emb = (const float*)d_in[1];
    const int N = in_sizes[1] / KD;
    const float* W1 = (const float*)d_in[2];
    const float* b1 = (const float*)d_in[3];
    const float* W2 = (const float*)d_in[4];
    const float* b2 = (const float*)d_in[5];
    const int* src = ei;        // edge_index[0]
    const int* dst = ei + E;    // edge_index[1]
    const int nbuck = (N + (1 << BSH) - 1) >> BSH;   // 391 for N=100000
    const int nchunk = (E + CHUNK - 1) / CHUNK;      // 782

    // ---- workspace layout ----
    char* p = (char*)d_ws;
    auto alloc = [&](size_t bytes) { char* q = p; p += (bytes + 255) & ~(size_t)255; return q; };
    unsigned short* h1 = (unsigned short*)alloc((size_t)N * 128 * sizeof(unsigned short)); // bf16
    unsigned short* x2 = (unsigned short*)alloc((size_t)N * 128 * sizeof(unsigned short)); // bf16
    int*   csr    = (int*)  alloc((size_t)nbuck * CAP * sizeof(int));
    int*   packed = (int*)  alloc((size_t)nbuck * CAP * sizeof(int));
    int*   ghist  = (int*)  alloc((size_t)nchunk * nbuck * sizeof(int));
    int*   roff   = (int*)  alloc((size_t)N * sizeof(int));
    int*   degN   = (int*)  alloc((size_t)N * sizeof(int));
    float* dinv   = (float*)alloc((size_t)N * sizeof(float));
    int*   bcur   = (int*)  alloc(MAXB * sizeof(int));
    unsigned short* Wt1 = (unsigned short*)alloc(128 * 128 * sizeof(unsigned short));
    unsigned short* Wt2 = (unsigned short*)alloc(64 * 128 * sizeof(unsigned short));
    unsigned short* h2 = h1;                        // bf16 [N,64], h1 dead after gather128

    // ---- build + layer1 matmul (overlapped) ----
    init_hist<<<nchunk, 256, 0, stream>>>(W1, W2, Wt1, Wt2, dst, ghist, E, nbuck);
    chunk_scan<<<nbuck, 256, 0, stream>>>(ghist, bcur, nchunk, nbuck);
    const int ngemm1 = (N + 63) / 64;
    scatter_gemm<<<nchunk + ngemm1, 256, 0, stream>>>(src, dst, ghist, packed, E,
                                                      nbuck, nchunk, emb, Wt1, h1, N);
    bucket_build<<<nbuck, 256, 0, stream>>>(packed, bcur, roff, degN, dinv, csr, N);

    // ---- layer 1 aggregate (per-edge dinv fma) ----
    gather128<<<(N + 3) / 4, 256, 0, stream>>>((const uint4*)h1, roff, degN, csr,
                                               dinv, b1, (uint4*)x2, N);

    // ---- layer 2 ----
    gemm_mfma64<<<(N + 63) / 64, 256, 0, stream>>>(x2, Wt2, dinv, h2, N);
    gather64<<<(N + 15) / 16, 256, 0, stream>>>((const uint4*)h2, roff, degN, csr,
                                                dinv, b2, (float4*)d_out, N);
}